// Round 8
// baseline (477.603 us; speedup 1.0000x reference)
//
#include <hip/hip_runtime.h>
#include <hip/hip_bf16.h>

using short8 = __attribute__((ext_vector_type(8))) short;
using f32x4  = __attribute__((ext_vector_type(4))) float;

#define KLP 136   // padded K=128 row stride for LSTM

__device__ __forceinline__ unsigned short f2bf(float f) {
  unsigned u = __float_as_uint(f);
  u += 0x7FFFu + ((u >> 16) & 1u);
  return (unsigned short)(u >> 16);
}
__device__ __forceinline__ unsigned pack2(float a, float b) {
  return (unsigned)f2bf(a) | ((unsigned)f2bf(b) << 16);
}
#if __has_builtin(__builtin_amdgcn_rcpf)
__device__ __forceinline__ float fast_rcp(float x) { return __builtin_amdgcn_rcpf(x); }
#else
__device__ __forceinline__ float fast_rcp(float x) { return 1.f / x; }
#endif
__device__ __forceinline__ float sigm(float x) { return fast_rcp(1.f + __expf(-x)); }
__device__ __forceinline__ float tanh_f(float x) { return fmaf(2.f, sigm(2.f * x), -1.f); }

// ---------------- prep_all: weight prep + x/ea converts + all zero-fills (one dispatch) ----------------
__global__ __launch_bounds__(256) void prep_all(
    const float* __restrict__ x,
    const float* __restrict__ ea,
    const float* __restrict__ W1_0, const float* __restrict__ Wih0,
    const float* __restrict__ bih0, const float* __restrict__ bhh0,
    const float* __restrict__ W1_1, const float* __restrict__ Wih1,
    const float* __restrict__ bih1, const float* __restrict__ bhh1,
    const float* __restrict__ W2_0, const float* __restrict__ Whh0, const float* __restrict__ b2_0,
    const float* __restrict__ W2_1, const float* __restrict__ Whh1, const float* __restrict__ b2_1,
    const float* __restrict__ gmW, const float* __restrict__ fmW,
    unsigned short* __restrict__ W1T,  // [2][64*160] out-major
    unsigned short* __restrict__ WcT,  // [2][256*128] out-major (merged)
    float* __restrict__ bG,            // [2][256]
    float* __restrict__ b2h,           // [2][256]
    unsigned short* __restrict__ WrT,  // [128][64]
    unsigned short* __restrict__ xb0,  // [N][64] bf16
    unsigned short* __restrict__ eaB,  // [E][32] bf16 (original order; L3-resident for scatter)
    float* __restrict__ aggrH,         // [N][64] zeroed here
    int* __restrict__ histA,           // [N]     zeroed here
    float* __restrict__ outZ, int nOut,
    int N, int E4)
{
  int t = blockIdx.x * 256 + threadIdx.x;

  // R0: weight transposes (61952 items)
  const int R0 = 2 * 26880 + 8192;
  if (t < R0) {
    const int per = 26880;
    if (t >= 2 * per) {
      int r2 = t - 2 * per;
      int o = r2 >> 6, k = r2 & 63;
      float v = 0.f;
      if (o < 50) v = gmW[k * 50 + o];
      else if (o >= 64 && o < 114) v = fmW[k * 50 + (o - 64)];
      WrT[o * 64 + k] = f2bf(v);
      return;
    }
    int step = t / per, r = t % per;
    const float* W1  = step ? W1_1 : W1_0;
    const float* Wih = step ? Wih1 : Wih0;
    const float* bih = step ? bih1 : bih0;
    const float* bhh = step ? bhh1 : bhh0;
    if (r < 10240) {
      int o = r / 160, k = r % 160;
      W1T[step * 10240 + o * 160 + k] = f2bf(W1[k * 64 + o]);
    } else if (r < 26624) {
      int rr = r - 10240;
      int g = rr >> 6, k = rr & 63;
      WcT[step * 32768 + g * 128 + k] = f2bf(Wih[k * 256 + g]);
    } else {
      int g = r - 26624;
      bG[step * 256 + g] = bih[g] + bhh[g];
    }
    return;
  }
  t -= R0;

  // R1: merged weight  Wc_h' = W2 @ Whh, b2h = b2 @ Whh (33280 items)
  const int R1 = 33280;
  if (t < R1) {
    if (t < 32768) {
      int step = t >> 14, r = t & 16383;
      int g = r >> 6, k = r & 63;
      const float* W2  = step ? W2_1 : W2_0;
      const float* Whh = step ? Whh1 : Whh0;
      float v = 0.f;
      for (int j = 0; j < 64; ++j) v = fmaf(W2[k * 64 + j], Whh[j * 256 + g], v);
      WcT[step * 32768 + g * 128 + 64 + k] = f2bf(v);
    } else {
      int r = t - 32768;
      int step = r >> 8, g = r & 255;
      const float* b2  = step ? b2_1 : b2_0;
      const float* Whh = step ? Whh1 : Whh0;
      float v = 0.f;
      for (int j = 0; j < 64; ++j) v = fmaf(b2[j], Whh[j * 256 + g], v);
      b2h[step * 256 + g] = v;
    }
    return;
  }
  t -= R1;

  // R2: convert_x, 8 elems/thread (N*8 items)
  const int R2 = N * 8;
  if (t < R2) {
    const float4* p = (const float4*)(x + (long long)t * 8);
    float4 a0 = p[0], a1 = p[1];
    *(uint4*)(xb0 + (long long)t * 8) =
        make_uint4(pack2(a0.x, a0.y), pack2(a0.z, a0.w), pack2(a1.x, a1.y), pack2(a1.z, a1.w));
    return;
  }
  t -= R2;

  // R3: zero aggrH as float4 (N*16 items)
  const int R3 = N * 16;
  if (t < R3) { ((float4*)aggrH)[t] = make_float4(0.f, 0.f, 0.f, 0.f); return; }
  t -= R3;

  // R4: zero histA as int4 (N/4 items)
  const int R4 = N / 4;
  if (t < R4) { ((int4*)histA)[t] = make_int4(0, 0, 0, 0); return; }
  t -= R4;

  // R5: zero output
  if (t < nOut) { outZ[t] = 0.f; return; }
  t -= nOut;

  // R6: convert ea f32 -> bf16, 8 elems/thread (E*4 items), coalesced both sides
  if (t < E4) {
    const float4* p = (const float4*)(ea + (long long)t * 8);
    float4 a0 = p[0], a1 = p[1];
    *(uint4*)(eaB + (long long)t * 8) =
        make_uint4(pack2(a0.x, a0.y), pack2(a0.z, a0.w), pack2(a1.x, a1.y), pack2(a1.z, a1.w));
  }
}

// ---------------- sort: hist -> 3-phase scan (+segment build) -> single-pass permute ----------------
__global__ __launch_bounds__(256) void hist_kernel(
    const int* __restrict__ dstI, int* __restrict__ hist, int E)
{
  int e = blockIdx.x * 256 + threadIdx.x;
  if (e < E) atomicAdd(&hist[dstI[e]], 1);
}

__global__ __launch_bounds__(256) void scan_part(
    const int* __restrict__ hist, int2* __restrict__ blockTot, int N)
{
  __shared__ int sD[256], sS[256];
  int t = threadIdx.x;
  int n = blockIdx.x * 256 + t;
  int d = (n < N) ? hist[n] : 0;
  int sg = (d + 15) >> 4;
  sD[t] = d; sS[t] = sg;
  __syncthreads();
  #pragma unroll
  for (int off = 128; off; off >>= 1) {
    if (t < off) { sD[t] += sD[t + off]; sS[t] += sS[t + off]; }
    __syncthreads();
  }
  if (t == 0) blockTot[blockIdx.x] = make_int2(sD[0], sS[0]);
}

__global__ __launch_bounds__(256) void scan_mid(
    const int2* __restrict__ blockTot, int2* __restrict__ blockBase,
    int* __restrict__ nSegTot, int nb)
{
  __shared__ int sD[256], sS[256];
  int t = threadIdx.x;
  int d = 0, s = 0;
  if (t < nb) { int2 v = blockTot[t]; d = v.x; s = v.y; }
  sD[t] = d; sS[t] = s;
  __syncthreads();
  #pragma unroll
  for (int off = 1; off < 256; off <<= 1) {
    int vd = (t >= off) ? sD[t - off] : 0;
    int vs = (t >= off) ? sS[t - off] : 0;
    __syncthreads();
    sD[t] += vd; sS[t] += vs;
    __syncthreads();
  }
  if (t < nb) blockBase[t] = make_int2(sD[t] - d, sS[t] - s);
  if (t == nb - 1) *nSegTot = sS[t];
}

__global__ __launch_bounds__(256) void scan_final(
    const int* __restrict__ hist, const int2* __restrict__ blockBase,
    int* __restrict__ cursor, int4* __restrict__ segInfo, int N)
{
  __shared__ int sD[256], sS[256];
  int t = threadIdx.x;
  int n = blockIdx.x * 256 + t;
  int d = (n < N) ? hist[n] : 0;
  int sg = (d + 15) >> 4;
  sD[t] = d; sS[t] = sg;
  __syncthreads();
  #pragma unroll
  for (int off = 1; off < 256; off <<= 1) {
    int vd = (t >= off) ? sD[t - off] : 0;
    int vs = (t >= off) ? sS[t - off] : 0;
    __syncthreads();
    sD[t] += vd; sS[t] += vs;
    __syncthreads();
  }
  if (n < N) {
    int2 bb = blockBase[blockIdx.x];
    int degBase = bb.x + sD[t] - d;
    int segBase = bb.y + sS[t] - sg;
    cursor[n] = degBase;
    for (int j = 0; j < sg; ++j)
      segInfo[segBase + j] = make_int4(degBase + j * 16, n, min(d - j * 16, 16), 0);
  }
}

// single-pass permute, 4 lanes per edge: leader does the atomic, __shfl broadcasts p.
// Source is pre-converted bf16 eaB (L3-resident) -> pure 16B copy, no pack VALU,
// near-zero HBM fetch. Each 64B row is one contiguous 4-lane store.
__global__ __launch_bounds__(256) void scatter_perm(
    const int* __restrict__ srcI, const int* __restrict__ dstI,
    const unsigned short* __restrict__ eaB, int* __restrict__ cursor,
    int* __restrict__ srcS, unsigned short* __restrict__ eaS, int E)
{
  const int t = threadIdx.x;
  const int l = t & 63;
  const int e = blockIdx.x * 64 + (t >> 2);
  const int c = t & 3;
  if (e >= E) return;
  int p = 0;
  if (c == 0) {
    int d = dstI[e];
    p = atomicAdd(&cursor[d], 1);
    srcS[p] = srcI[e];
  }
  p = __shfl(p, l & ~3);   // broadcast within the 4-lane group
  uint4 v = *(const uint4*)(eaB + (long long)e * 32 + c * 8);
  *(uint4*)(eaS + (long long)p * 32 + c * 8) = v;
}

// ---------------- edge GEMM: split B-stash (8 frags in regs, 12 in LDS), 1-inst atomic ----------------
// wave = one 16-edge segment of one dst node. Inner loop LDS issue: 12 ds_read_b128
// (was 20) vs 20 MFMA -- relieves the LDS-issue bound at +32 VGPR.
__global__ __launch_bounds__(256) void edge_gemm(
    const unsigned short* __restrict__ xb,     // [N][64] bf16
    const unsigned short* __restrict__ eaS,    // [E][32] bf16, dst-sorted
    const int* __restrict__ srcS,              // [E] dst-sorted
    const int4* __restrict__ segInfo,          // [nSeg] {start,node,cnt,_}
    const int* __restrict__ nSegPtr,
    const unsigned short* __restrict__ W1T,    // [64][160] bf16 out-major
    const float* __restrict__ b1,
    float* __restrict__ aggrH)                 // [N][64] f32 (pre-zeroed)
{
  __shared__ unsigned short stash[12 * 64 * 8];  // 12 KB: kc=2,3,4 fragments
  const int t = threadIdx.x;
  const int w = t >> 6, l = t & 63;
  const int quad = l >> 4, lr = l & 15;

  // kc=0,1 fragments live in registers (8 x short8 = 32 VGPR)
  short8 bF01[2][4];
  #pragma unroll
  for (int kc = 0; kc < 2; ++kc)
    #pragma unroll
    for (int n = 0; n < 4; ++n)
      bF01[kc][n] = *(const short8*)(W1T + (n * 16 + lr) * 160 + kc * 32 + quad * 8);

  #pragma unroll
  for (int p = 0; p < 3; ++p) {
    int idx = p * 256 + t;              // 0..767
    int grp = idx >> 6, ll = idx & 63;  // grp = (kc-2)*4+n
    int kc = 2 + (grp >> 2), n = grp & 3;
    *(uint4*)(stash + idx * 8) =
        *(const uint4*)(W1T + (n * 16 + (ll & 15)) * 160 + kc * 32 + (ll >> 4) * 8);
  }
  float bb[4];
  #pragma unroll
  for (int n = 0; n < 4; ++n) bb[n] = b1[n * 16 + lr];
  __syncthreads();

  const int nSeg = *nSegPtr;
  const int W = gridDim.x * 4;
  int s = blockIdx.x * 4 + w;
  if (s >= nSeg) return;
  int4 si = segInfo[s];
  int src = srcS[si.x + min(lr, si.z - 1)];   // first segment's src, loaded early

  while (true) {
    const int sn = s + W;
    const bool more = sn < nSeg;
    int4 si_n = si;
    if (more) si_n = segInfo[sn];   // prefetch next descriptor

    const int start = si.x, node = si.y, cnt = si.z;
    const int er = min(lr, cnt - 1);            // clamp pad rows to a valid edge

    const short8* pd = (const short8*)(xb + (long long)node * 64);
    const short8* ps = (const short8*)(xb + (long long)src * 64);
    short8 a0 = pd[quad];       // x[dst], k 0..31   (wave-uniform row)
    short8 a1 = pd[4 + quad];   // x[dst], k 32..63
    short8 a2 = ps[quad];       // x[src], k 64..95
    short8 a3 = ps[4 + quad];   // x[src], k 96..127
    short8 a4 = *(const short8*)(eaS + (long long)(start + er) * 32 + quad * 8);  // ea, coalesced

    // prefetch next segment's src index while MFMAs run
    int src_n = src;
    if (more) src_n = srcS[si_n.x + min(lr, si_n.z - 1)];

    f32x4 acc[4] = {};
    #pragma unroll
    for (int kc = 0; kc < 5; ++kc) {
      short8 aX = (kc == 0) ? a0 : (kc == 1) ? a1 : (kc == 2) ? a2 : (kc == 3) ? a3 : a4;
      #pragma unroll
      for (int n = 0; n < 4; ++n) {
        short8 bFr = (kc < 2)
            ? bF01[kc][n]
            : *(const short8*)(stash + (((((kc - 2) << 2)) | n) * 64 + l) * 8);
        acc[n] = __builtin_amdgcn_mfma_f32_16x16x32_bf16(aX, bFr, acc[n], 0, 0, 0);
      }
    }

    // relu + mask pad rows + reduce; one 64-lane atomic instruction per segment
    float myv = 0.f;
    #pragma unroll
    for (int n = 0; n < 4; ++n) {
      float sum = 0.f;
      #pragma unroll
      for (int rr = 0; rr < 4; ++rr) {
        float v = fmaxf(acc[n][rr] + bb[n], 0.f);
        sum += (quad * 4 + rr < cnt) ? v : 0.f;
      }
      sum += __shfl_xor(sum, 16);
      sum += __shfl_xor(sum, 32);
      if (quad == n) myv = sum;     // lane l owns output column l = quad*16+lr
    }
    unsafeAtomicAdd(&aggrH[(long long)node * 64 + l], myv);

    if (!more) break;
    s = sn; si = si_n; src = src_n;
  }
}

// ---------------- LSTM cell (+ optional fused readout on the final step) ----------------
__global__ __launch_bounds__(256) void lstm3(
    const unsigned short* __restrict__ xbin,  // [N][64] bf16
    float* __restrict__ aggrH,                // [N][64] f32 (Sum relu h1); re-zeroed if zeroAggr
    const float* __restrict__ cin,            // may be null (c=0)
    float* __restrict__ cout,
    const unsigned short* __restrict__ WcT,   // [256][128] bf16 out-major (merged)
    const float* __restrict__ bG,             // [256]
    const float* __restrict__ b2h,            // [256]
    const int* __restrict__ degA,             // [N]
    unsigned short* __restrict__ xbout,       // [N][64] bf16 (unused if doReadout)
    const unsigned short* __restrict__ WrT,   // [128][64] readout weights (doReadout only)
    const float* __restrict__ gb, const float* __restrict__ fb,
    float* __restrict__ outG,                 // [50] (doReadout only)
    int nNodes, int zeroAggr, int doReadout)
{
  __shared__ unsigned short sIn[64 * KLP];    // 8704 ush; reused as readout X [64][72]
  __shared__ unsigned short sW[128 * 72];     // 9216 ush >= 64*KLP; reused as readout W stash
  __shared__ float sBG[256], sB2h[256];       // reused as readout biases / partial out
  const int t = threadIdx.x;
  sBG[t] = bG[t];
  sB2h[t] = b2h[t];

  const int base_n = blockIdx.x * 64;
  const int nl = t >> 2, q = t & 3;
  const int node = base_n + nl;
  unsigned short* rowp = sIn + nl * KLP;
  if (node < nNodes) {
    const uint4* px = (const uint4*)(xbin + (long long)node * 64);
    *(uint4*)(rowp + q * 16)     = px[q * 2];
    *(uint4*)(rowp + q * 16 + 8) = px[q * 2 + 1];
    float4* pg = (float4*)(aggrH + (long long)node * 64) + q * 4;
    float4 g0 = pg[0], g1 = pg[1], g2 = pg[2], g3 = pg[3];
    *(uint4*)(rowp + 64 + q * 16) =
        make_uint4(pack2(g0.x, g0.y), pack2(g0.z, g0.w), pack2(g1.x, g1.y), pack2(g1.z, g1.w));
    *(uint4*)(rowp + 64 + q * 16 + 8) =
        make_uint4(pack2(g2.x, g2.y), pack2(g2.z, g2.w), pack2(g3.x, g3.y), pack2(g3.z, g3.w));
    if (zeroAggr) {  // re-zero for the next edge_gemm pass (saves a memset dispatch)
      float4 z = make_float4(0.f, 0.f, 0.f, 0.f);
      pg[0] = z; pg[1] = z; pg[2] = z; pg[3] = z;
    }
  } else {
    *(uint4*)(rowp + q * 16)          = make_uint4(0, 0, 0, 0);
    *(uint4*)(rowp + q * 16 + 8)      = make_uint4(0, 0, 0, 0);
    *(uint4*)(rowp + 64 + q * 16)     = make_uint4(0, 0, 0, 0);
    *(uint4*)(rowp + 64 + q * 16 + 8) = make_uint4(0, 0, 0, 0);
  }

  const int w = t >> 6, l = t & 63, quad = l >> 4, lr = l & 15;
  const int row0 = w * 16;
  f32x4 acc[16] = {};
  for (int grp = 0; grp < 4; ++grp) {
    const uint4* gw = (const uint4*)WcT + (long long)(grp * 64) * 16;  // 16 uint4/row
    uint4* lw = (uint4*)sW;                                            // 17/row padded
    {
      int o0 = t >> 4, s4 = t & 15;
      #pragma unroll
      for (int pp = 0; pp < 4; ++pp) {
        int o = pp * 16 + o0;
        lw[o * 17 + s4] = gw[o * 16 + s4];
      }
    }
    __syncthreads();
    #pragma unroll
    for (int kc = 0; kc < 4; ++kc) {
      short8 aF = *(const short8*)(sIn + (row0 + lr) * KLP + kc * 32 + quad * 8);
      #pragma unroll
      for (int nt = 0; nt < 4; ++nt) {
        short8 bF = *(const short8*)(sW + (nt * 16 + lr) * KLP + kc * 32 + quad * 8);
        acc[grp * 4 + nt] = __builtin_amdgcn_mfma_f32_16x16x32_bf16(aF, bF, acc[grp * 4 + nt], 0, 0, 0);
      }
    }
    __syncthreads();
  }

  #pragma unroll
  for (int nt = 0; nt < 4; ++nt) {
    #pragma unroll
    for (int rr = 0; rr < 4; ++rr) {
      int node2 = base_n + row0 + quad * 4 + rr;
      int rl = row0 + quad * 4 + rr;          // block-local row 0..63
      int col = nt * 16 + lr;
      if (node2 < nNodes) {
        long long off = (long long)node2 * 64 + col;
        float dg = (float)degA[node2];
        float iv = acc[nt][rr]      + sBG[col]       + dg * sB2h[col];
        float fv = acc[4 + nt][rr]  + sBG[64 + col]  + dg * sB2h[64 + col];
        float gv = acc[8 + nt][rr]  + sBG[128 + col] + dg * sB2h[128 + col];
        float ov = acc[12 + nt][rr] + sBG[192 + col] + dg * sB2h[192 + col];
        float cOld = cin ? cin[off] : 0.f;
        float cN = sigm(fv) * cOld + sigm(iv) * tanh_f(gv);
        float hN = sigm(ov) * tanh_f(cN);
        if (doReadout) {
          sIn[rl * 72 + col] = f2bf(hN);     // stage h for in-kernel readout
        } else {
          cout[off] = cN;
          xbout[off] = f2bf(hN);
        }
      } else if (doReadout) {
        sIn[rl * 72 + col] = 0;
      }
    }
  }

  if (!doReadout) return;

  // ---------------- fused readout phase (reuses all LDS) ----------------
  __syncthreads();
  {
    const uint4* gw = (const uint4*)WrT;  // 1024 uint4
    uint4* lw = (uint4*)sW;               // 9/row padded -> 72-ush row stride
    #pragma unroll
    for (int pp = 0; pp < 4; ++pp) {
      int idx = t + pp * 256;
      int o = idx >> 3, s = idx & 7;
      lw[o * 9 + s] = gw[idx];
    }
  }
  if (t < 64) {
    sBG[t]      = (t < 50) ? gb[t] : 0.f;   // sGb
    sBG[64 + t] = (t < 50) ? fb[t] : 0.f;   // sFb
  }
  __syncthreads();

  f32x4 racc[8] = {};
  #pragma unroll
  for (int kc = 0; kc < 2; ++kc) {
    short8 aF = *(const short8*)(sIn + (w * 16 + lr) * 72 + kc * 32 + quad * 8);
    #pragma unroll
    for (int n = 0; n < 8; ++n) {
      short8 bF = *(const short8*)(sW + (n * 16 + lr) * 72 + kc * 32 + quad * 8);
      racc[n] = __builtin_amdgcn_mfma_f32_16x16x32_bf16(aF, bF, racc[n], 0, 0, 0);
    }
  }
  float* sOutF = sB2h;   // [4][64] partials
  #pragma unroll
  for (int n = 0; n < 4; ++n) {
    float val = 0.f;
    #pragma unroll
    for (int rr = 0; rr < 4; ++rr) {
      int nd = base_n + w * 16 + quad * 4 + rr;
      if (nd < nNodes) {
        int jj = n * 16 + lr;
        float gv = sigm(racc[n][rr] + sBG[jj]);
        float fv = racc[n + 4][rr] + sBG[64 + jj];
        val += gv * fv;
      }
    }
    val += __shfl_xor(val, 16);
    val += __shfl_xor(val, 32);
    if (quad == 0) sOutF[w * 64 + n * 16 + lr] = val;
  }
  __syncthreads();
  if (t < 50) {
    float sm = sOutF[t] + sOutF[64 + t] + sOutF[128 + t] + sOutF[192 + t];
    unsafeAtomicAdd(&outG[t], sm);
  }
}

extern "C" void kernel_launch(void* const* d_in, const int* in_sizes, int n_in,
                              void* d_out, int out_size, void* d_ws, size_t ws_size,
                              hipStream_t stream)
{
  const float* x      = (const float*)d_in[0];
  const float* ea     = (const float*)d_in[1];
  const int*   ei     = (const int*)d_in[2];
  const float* fe0_W1 = (const float*)d_in[3];
  const float* fe0_b1 = (const float*)d_in[4];
  const float* fe0_W2 = (const float*)d_in[5];
  const float* fe0_b2 = (const float*)d_in[6];
  const float* l0_Wih = (const float*)d_in[7];
  const float* l0_Whh = (const float*)d_in[8];
  const float* l0_bih = (const float*)d_in[9];
  const float* l0_bhh = (const float*)d_in[10];
  const float* fe1_W1 = (const float*)d_in[11];
  const float* fe1_b1 = (const float*)d_in[12];
  const float* fe1_W2 = (const float*)d_in[13];
  const float* fe1_b2 = (const float*)d_in[14];
  const float* l1_Wih = (const float*)d_in[15];
  const float* l1_Whh = (const float*)d_in[16];
  const float* l1_bih = (const float*)d_in[17];
  const float* l1_bhh = (const float*)d_in[18];
  const float* gm_W   = (const float*)d_in[19];
  const float* gm_b   = (const float*)d_in[20];
  const float* fm_W   = (const float*)d_in[21];
  const float* fm_b   = (const float*)d_in[22];

  const int N = in_sizes[0] / 64;    // 50000
  const int E = in_sizes[1] / 32;    // 800000
  const int* srcI = ei;
  const int* dstI = ei + E;

  char* ws = (char*)d_ws;
  unsigned short* xb0     = (unsigned short*)(ws + 0);           //  6,400,000
  unsigned short* xb1     = (unsigned short*)(ws + 6400000);     //  6,400,000
  float*          aggrH   = (float*)(ws + 12800000);             // 12,800,000
  float*          cbuf    = (float*)(ws + 25600000);             // 12,800,000
  unsigned short* eaS     = (unsigned short*)(ws + 38400000);    // 51,200,000
  int*            srcS    = (int*)(ws + 89601024);               //  3,200,000 (+1KB slack)
  int4*           segInfo = (int4*)(ws + 92801088);              //  1,600,128
  int*            histA   = (int*)(ws + 94401280);               //    200,000
  int*            curA    = (int*)(ws + 94601280);               //    200,000
  unsigned short* W1T     = (unsigned short*)(ws + 94801280);    //     40,960
  unsigned short* WcT     = (unsigned short*)(ws + 94842240);    //    131,072
  float*          bG      = (float*)(ws + 94973312);             //      2,048
  float*          b2h     = (float*)(ws + 94975360);             //      2,048
  unsigned short* WrT     = (unsigned short*)(ws + 94977408);    //     16,384
  int*            nSegPtr = (int*)(ws + 94993792);               //          4 (+60 pad)
  int2*           blockTot  = (int2*)(ws + 94993856);            //      2,048
  int2*           blockBase = (int2*)(ws + 94995904);            //      2,048
  unsigned short* eaB     = (unsigned short*)(ws + 100000000);   // 51,200,000 bf16 ea (orig order)

  // prep_all covers: weight prep (61952) + merge (33280) + x-convert (N*8)
  //   + aggrH zero (N*16) + histA zero (N/4) + out zero (out_size) + ea-convert (E*4)
  const int E4 = E * 4;
  const int prepT = (2 * 26880 + 8192) + 33280 + N * 8 + N * 16 + N / 4 + out_size + E4;
  prep_all<<<(prepT + 255) / 256, 256, 0, stream>>>(
      x, ea,
      fe0_W1, l0_Wih, l0_bih, l0_bhh,
      fe1_W1, l1_Wih, l1_bih, l1_bhh,
      fe0_W2, l0_Whh, fe0_b2,
      fe1_W2, l1_Whh, fe1_b2,
      gm_W, fm_W,
      W1T, WcT, bG, b2h, WrT, xb0, eaB,
      aggrH, histA, (float*)d_out, out_size, N, E4);

  const int nb = (N + 255) / 256;
  hist_kernel<<<(E + 255) / 256, 256, 0, stream>>>(dstI, histA, E);
  scan_part<<<nb, 256, 0, stream>>>(histA, blockTot, N);
  scan_mid<<<1, 256, 0, stream>>>(blockTot, blockBase, nSegPtr, nb);
  scan_final<<<nb, 256, 0, stream>>>(histA, blockBase, curA, segInfo, N);
  scatter_perm<<<(E + 63) / 64, 256, 0, stream>>>(srcI, dstI, eaB, curA, srcS, eaS, E);

  const int nodeBlocks = (N + 63) / 64;

  // step 0 (lstm3 re-zeroes aggrH for step 1)
  edge_gemm<<<2048, 256, 0, stream>>>(xb0, eaS, srcS, segInfo, nSegPtr,
                                      W1T, fe0_b1, aggrH);
  lstm3<<<nodeBlocks, 256, 0, stream>>>(xb0, aggrH, nullptr, cbuf, WcT, bG, b2h,
                                        histA, xb1, WrT, gm_b, fm_b, (float*)d_out,
                                        N, 1, 0);

  // step 1: LSTM + fused readout (no xb/cbuf writes, no separate readout kernel)
  edge_gemm<<<2048, 256, 0, stream>>>(xb1, eaS, srcS, segInfo, nSegPtr,
                                      W1T + 10240, fe1_b1, aggrH);
  lstm3<<<nodeBlocks, 256, 0, stream>>>(xb1, aggrH, cbuf, nullptr, WcT + 32768,
                                        bG + 256, b2h + 256, histA, nullptr,
                                        WrT, gm_b, fm_b, (float*)d_out,
                                        N, 0, 1);
}

// Round 10
// 447.558 us; speedup vs baseline: 1.0671x; 1.0671x over previous
//
#include <hip/hip_runtime.h>
#include <hip/hip_bf16.h>

using short8 = __attribute__((ext_vector_type(8))) short;
using f32x4  = __attribute__((ext_vector_type(4))) float;
using uint4v = __attribute__((ext_vector_type(4))) unsigned;  // native vector for nt-store builtin

#define KLP 136   // padded K=128 row stride for LSTM

__device__ __forceinline__ unsigned short f2bf(float f) {
  unsigned u = __float_as_uint(f);
  u += 0x7FFFu + ((u >> 16) & 1u);
  return (unsigned short)(u >> 16);
}
__device__ __forceinline__ unsigned pack2(float a, float b) {
  return (unsigned)f2bf(a) | ((unsigned)f2bf(b) << 16);
}
#if __has_builtin(__builtin_amdgcn_rcpf)
__device__ __forceinline__ float fast_rcp(float x) { return __builtin_amdgcn_rcpf(x); }
#else
__device__ __forceinline__ float fast_rcp(float x) { return 1.f / x; }
#endif
__device__ __forceinline__ float sigm(float x) { return fast_rcp(1.f + __expf(-x)); }
__device__ __forceinline__ float tanh_f(float x) { return fmaf(2.f, sigm(2.f * x), -1.f); }

// ---------------- prep_all: weight prep + x convert + all zero-fills (one dispatch) ----------------
__global__ __launch_bounds__(256) void prep_all(
    const float* __restrict__ x,
    const float* __restrict__ W1_0, const float* __restrict__ Wih0,
    const float* __restrict__ bih0, const float* __restrict__ bhh0,
    const float* __restrict__ W1_1, const float* __restrict__ Wih1,
    const float* __restrict__ bih1, const float* __restrict__ bhh1,
    const float* __restrict__ W2_0, const float* __restrict__ Whh0, const float* __restrict__ b2_0,
    const float* __restrict__ W2_1, const float* __restrict__ Whh1, const float* __restrict__ b2_1,
    const float* __restrict__ gmW, const float* __restrict__ fmW,
    unsigned short* __restrict__ W1T,  // [2][64*160] out-major
    unsigned short* __restrict__ WcT,  // [2][256*128] out-major (merged)
    float* __restrict__ bG,            // [2][256]
    float* __restrict__ b2h,           // [2][256]
    unsigned short* __restrict__ WrT,  // [128][64]
    unsigned short* __restrict__ xb0,  // [N][64] bf16
    float* __restrict__ aggrH,         // [N][64] zeroed here
    int* __restrict__ histA,           // [N]     zeroed here
    float* __restrict__ outZ, int nOut,
    int N)
{
  int t = blockIdx.x * 256 + threadIdx.x;

  // R0: weight transposes (61952 items)
  const int R0 = 2 * 26880 + 8192;
  if (t < R0) {
    const int per = 26880;
    if (t >= 2 * per) {
      int r2 = t - 2 * per;
      int o = r2 >> 6, k = r2 & 63;
      float v = 0.f;
      if (o < 50) v = gmW[k * 50 + o];
      else if (o >= 64 && o < 114) v = fmW[k * 50 + (o - 64)];
      WrT[o * 64 + k] = f2bf(v);
      return;
    }
    int step = t / per, r = t % per;
    const float* W1  = step ? W1_1 : W1_0;
    const float* Wih = step ? Wih1 : Wih0;
    const float* bih = step ? bih1 : bih0;
    const float* bhh = step ? bhh1 : bhh0;
    if (r < 10240) {
      int o = r / 160, k = r % 160;
      W1T[step * 10240 + o * 160 + k] = f2bf(W1[k * 64 + o]);
    } else if (r < 26624) {
      int rr = r - 10240;
      int g = rr >> 6, k = rr & 63;
      WcT[step * 32768 + g * 128 + k] = f2bf(Wih[k * 256 + g]);
    } else {
      int g = r - 26624;
      bG[step * 256 + g] = bih[g] + bhh[g];
    }
    return;
  }
  t -= R0;

  // R1: merged weight  Wc_h' = W2 @ Whh, b2h = b2 @ Whh (33280 items)
  const int R1 = 33280;
  if (t < R1) {
    if (t < 32768) {
      int step = t >> 14, r = t & 16383;
      int g = r >> 6, k = r & 63;
      const float* W2  = step ? W2_1 : W2_0;
      const float* Whh = step ? Whh1 : Whh0;
      float v = 0.f;
      for (int j = 0; j < 64; ++j) v = fmaf(W2[k * 64 + j], Whh[j * 256 + g], v);
      WcT[step * 32768 + g * 128 + 64 + k] = f2bf(v);
    } else {
      int r = t - 32768;
      int step = r >> 8, g = r & 255;
      const float* b2  = step ? b2_1 : b2_0;
      const float* Whh = step ? Whh1 : Whh0;
      float v = 0.f;
      for (int j = 0; j < 64; ++j) v = fmaf(b2[j], Whh[j * 256 + g], v);
      b2h[step * 256 + g] = v;
    }
    return;
  }
  t -= R1;

  // R2: convert_x, 8 elems/thread (N*8 items)
  const int R2 = N * 8;
  if (t < R2) {
    const float4* p = (const float4*)(x + (long long)t * 8);
    float4 a0 = p[0], a1 = p[1];
    *(uint4*)(xb0 + (long long)t * 8) =
        make_uint4(pack2(a0.x, a0.y), pack2(a0.z, a0.w), pack2(a1.x, a1.y), pack2(a1.z, a1.w));
    return;
  }
  t -= R2;

  // R3: zero aggrH as float4 (N*16 items)
  const int R3 = N * 16;
  if (t < R3) { ((float4*)aggrH)[t] = make_float4(0.f, 0.f, 0.f, 0.f); return; }
  t -= R3;

  // R4: zero histA as int4 (N/4 items)
  const int R4 = N / 4;
  if (t < R4) { ((int4*)histA)[t] = make_int4(0, 0, 0, 0); return; }
  t -= R4;

  // R5: zero output
  if (t < nOut) outZ[t] = 0.f;
}

// ---------------- sort: hist -> 3-phase scan (+segment build) -> single-pass permute ----------------
__global__ __launch_bounds__(256) void hist_kernel(
    const int* __restrict__ dstI, int* __restrict__ hist, int E)
{
  int e = blockIdx.x * 256 + threadIdx.x;
  if (e < E) atomicAdd(&hist[dstI[e]], 1);
}

__global__ __launch_bounds__(256) void scan_part(
    const int* __restrict__ hist, int2* __restrict__ blockTot, int N)
{
  __shared__ int sD[256], sS[256];
  int t = threadIdx.x;
  int n = blockIdx.x * 256 + t;
  int d = (n < N) ? hist[n] : 0;
  int sg = (d + 15) >> 4;
  sD[t] = d; sS[t] = sg;
  __syncthreads();
  #pragma unroll
  for (int off = 128; off; off >>= 1) {
    if (t < off) { sD[t] += sD[t + off]; sS[t] += sS[t + off]; }
    __syncthreads();
  }
  if (t == 0) blockTot[blockIdx.x] = make_int2(sD[0], sS[0]);
}

__global__ __launch_bounds__(256) void scan_mid(
    const int2* __restrict__ blockTot, int2* __restrict__ blockBase,
    int* __restrict__ nSegTot, int nb)
{
  __shared__ int sD[256], sS[256];
  int t = threadIdx.x;
  int d = 0, s = 0;
  if (t < nb) { int2 v = blockTot[t]; d = v.x; s = v.y; }
  sD[t] = d; sS[t] = s;
  __syncthreads();
  #pragma unroll
  for (int off = 1; off < 256; off <<= 1) {
    int vd = (t >= off) ? sD[t - off] : 0;
    int vs = (t >= off) ? sS[t - off] : 0;
    __syncthreads();
    sD[t] += vd; sS[t] += vs;
    __syncthreads();
  }
  if (t < nb) blockBase[t] = make_int2(sD[t] - d, sS[t] - s);
  if (t == nb - 1) *nSegTot = sS[t];
}

__global__ __launch_bounds__(256) void scan_final(
    const int* __restrict__ hist, const int2* __restrict__ blockBase,
    int* __restrict__ cursor, int4* __restrict__ segInfo, int N)
{
  __shared__ int sD[256], sS[256];
  int t = threadIdx.x;
  int n = blockIdx.x * 256 + t;
  int d = (n < N) ? hist[n] : 0;
  int sg = (d + 15) >> 4;
  sD[t] = d; sS[t] = sg;
  __syncthreads();
  #pragma unroll
  for (int off = 1; off < 256; off <<= 1) {
    int vd = (t >= off) ? sD[t - off] : 0;
    int vs = (t >= off) ? sS[t - off] : 0;
    __syncthreads();
    sD[t] += vd; sS[t] += vs;
    __syncthreads();
  }
  if (n < N) {
    int2 bb = blockBase[blockIdx.x];
    int degBase = bb.x + sD[t] - d;
    int segBase = bb.y + sS[t] - sg;
    cursor[n] = degBase;
    for (int j = 0; j < sg; ++j)
      segInfo[segBase + j] = make_int4(degBase + j * 16, n, min(d - j * 16, 16), 0);
  }
}

// single-pass permute, 4 lanes per edge: leader does the atomic, __shfl broadcasts p.
// eaS rows stored NON-TEMPORALLY (native ext_vector type for the builtin):
// bypasses L2 write-allocate -- the measured 2x write amplification (102MB
// writeback for a 51MB payload) was fetch-line + full-line writeback.
__global__ __launch_bounds__(256) void scatter_perm(
    const int* __restrict__ srcI, const int* __restrict__ dstI,
    const float* __restrict__ ea, int* __restrict__ cursor,
    int* __restrict__ srcS, unsigned short* __restrict__ eaS, int E)
{
  const int t = threadIdx.x;
  const int l = t & 63;
  const int e = blockIdx.x * 64 + (t >> 2);
  const int c = t & 3;
  if (e >= E) return;
  int p = 0;
  if (c == 0) {
    int d = dstI[e];
    p = atomicAdd(&cursor[d], 1);
    srcS[p] = srcI[e];
  }
  p = __shfl(p, l & ~3);   // broadcast within the 4-lane group
  const float4* pe = (const float4*)(ea + (long long)e * 32 + c * 8);
  float4 a0 = pe[0], a1 = pe[1];
  uint4v v;
  v.x = pack2(a0.x, a0.y); v.y = pack2(a0.z, a0.w);
  v.z = pack2(a1.x, a1.y); v.w = pack2(a1.z, a1.w);
  __builtin_nontemporal_store(v, (uint4v*)(eaS + (long long)p * 32 + c * 8));
}

// ---------------- edge GEMM: LDS W1-stash (<=64 VGPR, 8 waves/SIMD), coalesced eaS ----------------
// wave = one 16-edge segment of one dst node. NOTE: do NOT add registers here --
// round-8's +32-VGPR split-stash crossed the 64-VGPR occupancy cliff (+25us).
__global__ __launch_bounds__(256) void edge_gemm(
    const unsigned short* __restrict__ xb,     // [N][64] bf16
    const unsigned short* __restrict__ eaS,    // [E][32] bf16, dst-sorted
    const int* __restrict__ srcS,              // [E] dst-sorted
    const int4* __restrict__ segInfo,          // [nSeg] {start,node,cnt,_}
    const int* __restrict__ nSegPtr,
    const unsigned short* __restrict__ W1T,    // [64][160] bf16 out-major
    const float* __restrict__ b1,
    float* __restrict__ aggrH)                 // [N][64] f32 (pre-zeroed)
{
  // W1 fragment stash: [grp = kc*4+n][lane][8 bf16] -> each MFMA B-operand is
  // one lane-linear ds_read_b128 (conflict-free); frees ~80 regs vs reg stash.
  __shared__ unsigned short stash[20 * 64 * 8];  // 20 KB
  const int t = threadIdx.x;
  const int w = t >> 6, l = t & 63;
  const int quad = l >> 4, lr = l & 15;

  #pragma unroll
  for (int p = 0; p < 5; ++p) {
    int idx = p * 256 + t;              // 0..1279
    int grp = idx >> 6, ll = idx & 63;  // grp = kc*4+n
    int kc = grp >> 2, n = grp & 3;
    *(uint4*)(stash + idx * 8) =
        *(const uint4*)(W1T + (n * 16 + (ll & 15)) * 160 + kc * 32 + (ll >> 4) * 8);
  }
  float bb[4];
  #pragma unroll
  for (int n = 0; n < 4; ++n) bb[n] = b1[n * 16 + lr];
  __syncthreads();

  const int nSeg = *nSegPtr;
  const int W = gridDim.x * 4;
  int s = blockIdx.x * 4 + w;
  if (s >= nSeg) return;
  int4 si = segInfo[s];
  int src = srcS[si.x + min(lr, si.z - 1)];   // first segment's src, loaded early

  while (true) {
    const int sn = s + W;
    const bool more = sn < nSeg;
    int4 si_n = si;
    if (more) si_n = segInfo[sn];   // prefetch next descriptor

    const int start = si.x, node = si.y, cnt = si.z;
    const int er = min(lr, cnt - 1);            // clamp pad rows to a valid edge

    const short8* pd = (const short8*)(xb + (long long)node * 64);
    const short8* ps = (const short8*)(xb + (long long)src * 64);
    short8 a0 = pd[quad];       // x[dst], k 0..31   (wave-uniform row)
    short8 a1 = pd[4 + quad];   // x[dst], k 32..63
    short8 a2 = ps[quad];       // x[src], k 64..95
    short8 a3 = ps[4 + quad];   // x[src], k 96..127
    short8 a4 = *(const short8*)(eaS + (long long)(start + er) * 32 + quad * 8);  // ea, coalesced

    // prefetch next segment's src index while MFMAs run
    int src_n = src;
    if (more) src_n = srcS[si_n.x + min(lr, si_n.z - 1)];

    f32x4 acc[4] = {};
    #pragma unroll
    for (int kc = 0; kc < 5; ++kc) {
      short8 aX = (kc == 0) ? a0 : (kc == 1) ? a1 : (kc == 2) ? a2 : (kc == 3) ? a3 : a4;
      #pragma unroll
      for (int n = 0; n < 4; ++n) {
        short8 bFr = *(const short8*)(stash + (((kc << 2) | n) * 64 + l) * 8);
        acc[n] = __builtin_amdgcn_mfma_f32_16x16x32_bf16(aX, bFr, acc[n], 0, 0, 0);
      }
    }

    // relu + mask pad rows + reduce; one 64-lane atomic instruction per segment
    float myv = 0.f;
    #pragma unroll
    for (int n = 0; n < 4; ++n) {
      float sum = 0.f;
      #pragma unroll
      for (int rr = 0; rr < 4; ++rr) {
        float v = fmaxf(acc[n][rr] + bb[n], 0.f);
        sum += (quad * 4 + rr < cnt) ? v : 0.f;
      }
      sum += __shfl_xor(sum, 16);
      sum += __shfl_xor(sum, 32);
      if (quad == n) myv = sum;     // lane l owns output column l = quad*16+lr
    }
    unsafeAtomicAdd(&aggrH[(long long)node * 64 + l], myv);

    if (!more) break;
    s = sn; si = si_n; src = src_n;
  }
}

// ---------------- LSTM cell (+ optional fused readout on the final step) ----------------
__global__ __launch_bounds__(256) void lstm3(
    const unsigned short* __restrict__ xbin,  // [N][64] bf16
    float* __restrict__ aggrH,                // [N][64] f32 (Sum relu h1); re-zeroed if zeroAggr
    const float* __restrict__ cin,            // may be null (c=0)
    float* __restrict__ cout,
    const unsigned short* __restrict__ WcT,   // [256][128] bf16 out-major (merged)
    const float* __restrict__ bG,             // [256]
    const float* __restrict__ b2h,            // [256]
    const int* __restrict__ degA,             // [N]
    unsigned short* __restrict__ xbout,       // [N][64] bf16 (unused if doReadout)
    const unsigned short* __restrict__ WrT,   // [128][64] readout weights (doReadout only)
    const float* __restrict__ gb, const float* __restrict__ fb,
    float* __restrict__ outG,                 // [50] (doReadout only)
    int nNodes, int zeroAggr, int doReadout)
{
  __shared__ unsigned short sIn[64 * KLP];    // 8704 ush; reused as readout X [64][72]
  __shared__ unsigned short sW[128 * 72];     // 9216 ush >= 64*KLP; reused as readout W stash
  __shared__ float sBG[256], sB2h[256];       // reused as readout biases / partial out
  const int t = threadIdx.x;
  sBG[t] = bG[t];
  sB2h[t] = b2h[t];

  const int base_n = blockIdx.x * 64;
  const int nl = t >> 2, q = t & 3;
  const int node = base_n + nl;
  unsigned short* rowp = sIn + nl * KLP;
  if (node < nNodes) {
    const uint4* px = (const uint4*)(xbin + (long long)node * 64);
    *(uint4*)(rowp + q * 16)     = px[q * 2];
    *(uint4*)(rowp + q * 16 + 8) = px[q * 2 + 1];
    float4* pg = (float4*)(aggrH + (long long)node * 64) + q * 4;
    float4 g0 = pg[0], g1 = pg[1], g2 = pg[2], g3 = pg[3];
    *(uint4*)(rowp + 64 + q * 16) =
        make_uint4(pack2(g0.x, g0.y), pack2(g0.z, g0.w), pack2(g1.x, g1.y), pack2(g1.z, g1.w));
    *(uint4*)(rowp + 64 + q * 16 + 8) =
        make_uint4(pack2(g2.x, g2.y), pack2(g2.z, g2.w), pack2(g3.x, g3.y), pack2(g3.z, g3.w));
    if (zeroAggr) {  // re-zero for the next edge_gemm pass (saves a memset dispatch)
      float4 z = make_float4(0.f, 0.f, 0.f, 0.f);
      pg[0] = z; pg[1] = z; pg[2] = z; pg[3] = z;
    }
  } else {
    *(uint4*)(rowp + q * 16)          = make_uint4(0, 0, 0, 0);
    *(uint4*)(rowp + q * 16 + 8)      = make_uint4(0, 0, 0, 0);
    *(uint4*)(rowp + 64 + q * 16)     = make_uint4(0, 0, 0, 0);
    *(uint4*)(rowp + 64 + q * 16 + 8) = make_uint4(0, 0, 0, 0);
  }

  const int w = t >> 6, l = t & 63, quad = l >> 4, lr = l & 15;
  const int row0 = w * 16;
  f32x4 acc[16] = {};
  for (int grp = 0; grp < 4; ++grp) {
    const uint4* gw = (const uint4*)WcT + (long long)(grp * 64) * 16;  // 16 uint4/row
    uint4* lw = (uint4*)sW;                                            // 17/row padded
    {
      int o0 = t >> 4, s4 = t & 15;
      #pragma unroll
      for (int pp = 0; pp < 4; ++pp) {
        int o = pp * 16 + o0;
        lw[o * 17 + s4] = gw[o * 16 + s4];
      }
    }
    __syncthreads();
    #pragma unroll
    for (int kc = 0; kc < 4; ++kc) {
      short8 aF = *(const short8*)(sIn + (row0 + lr) * KLP + kc * 32 + quad * 8);
      #pragma unroll
      for (int nt = 0; nt < 4; ++nt) {
        short8 bF = *(const short8*)(sW + (nt * 16 + lr) * KLP + kc * 32 + quad * 8);
        acc[grp * 4 + nt] = __builtin_amdgcn_mfma_f32_16x16x32_bf16(aF, bF, acc[grp * 4 + nt], 0, 0, 0);
      }
    }
    __syncthreads();
  }

  #pragma unroll
  for (int nt = 0; nt < 4; ++nt) {
    #pragma unroll
    for (int rr = 0; rr < 4; ++rr) {
      int node2 = base_n + row0 + quad * 4 + rr;
      int rl = row0 + quad * 4 + rr;          // block-local row 0..63
      int col = nt * 16 + lr;
      if (node2 < nNodes) {
        long long off = (long long)node2 * 64 + col;
        float dg = (float)degA[node2];
        float iv = acc[nt][rr]      + sBG[col]       + dg * sB2h[col];
        float fv = acc[4 + nt][rr]  + sBG[64 + col]  + dg * sB2h[64 + col];
        float gv = acc[8 + nt][rr]  + sBG[128 + col] + dg * sB2h[128 + col];
        float ov = acc[12 + nt][rr] + sBG[192 + col] + dg * sB2h[192 + col];
        float cOld = cin ? cin[off] : 0.f;
        float cN = sigm(fv) * cOld + sigm(iv) * tanh_f(gv);
        float hN = sigm(ov) * tanh_f(cN);
        if (doReadout) {
          sIn[rl * 72 + col] = f2bf(hN);     // stage h for in-kernel readout
        } else {
          cout[off] = cN;
          xbout[off] = f2bf(hN);
        }
      } else if (doReadout) {
        sIn[rl * 72 + col] = 0;
      }
    }
  }

  if (!doReadout) return;

  // ---------------- fused readout phase (reuses all LDS) ----------------
  __syncthreads();
  {
    const uint4* gw = (const uint4*)WrT;  // 1024 uint4
    uint4* lw = (uint4*)sW;               // 9/row padded -> 72-ush row stride
    #pragma unroll
    for (int pp = 0; pp < 4; ++pp) {
      int idx = t + pp * 256;
      int o = idx >> 3, s = idx & 7;
      lw[o * 9 + s] = gw[idx];
    }
  }
  if (t < 64) {
    sBG[t]      = (t < 50) ? gb[t] : 0.f;   // sGb
    sBG[64 + t] = (t < 50) ? fb[t] : 0.f;   // sFb
  }
  __syncthreads();

  f32x4 racc[8] = {};
  #pragma unroll
  for (int kc = 0; kc < 2; ++kc) {
    short8 aF = *(const short8*)(sIn + (w * 16 + lr) * 72 + kc * 32 + quad * 8);
    #pragma unroll
    for (int n = 0; n < 8; ++n) {
      short8 bF = *(const short8*)(sW + (n * 16 + lr) * 72 + kc * 32 + quad * 8);
      racc[n] = __builtin_amdgcn_mfma_f32_16x16x32_bf16(aF, bF, racc[n], 0, 0, 0);
    }
  }
  float* sOutF = sB2h;   // [4][64] partials
  #pragma unroll
  for (int n = 0; n < 4; ++n) {
    float val = 0.f;
    #pragma unroll
    for (int rr = 0; rr < 4; ++rr) {
      int nd = base_n + w * 16 + quad * 4 + rr;
      if (nd < nNodes) {
        int jj = n * 16 + lr;
        float gv = sigm(racc[n][rr] + sBG[jj]);
        float fv = racc[n + 4][rr] + sBG[64 + jj];
        val += gv * fv;
      }
    }
    val += __shfl_xor(val, 16);
    val += __shfl_xor(val, 32);
    if (quad == 0) sOutF[w * 64 + n * 16 + lr] = val;
  }
  __syncthreads();
  if (t < 50) {
    float sm = sOutF[t] + sOutF[64 + t] + sOutF[128 + t] + sOutF[192 + t];
    unsafeAtomicAdd(&outG[t], sm);
  }
}

extern "C" void kernel_launch(void* const* d_in, const int* in_sizes, int n_in,
                              void* d_out, int out_size, void* d_ws, size_t ws_size,
                              hipStream_t stream)
{
  const float* x      = (const float*)d_in[0];
  const float* ea     = (const float*)d_in[1];
  const int*   ei     = (const int*)d_in[2];
  const float* fe0_W1 = (const float*)d_in[3];
  const float* fe0_b1 = (const float*)d_in[4];
  const float* fe0_W2 = (const float*)d_in[5];
  const float* fe0_b2 = (const float*)d_in[6];
  const float* l0_Wih = (const float*)d_in[7];
  const float* l0_Whh = (const float*)d_in[8];
  const float* l0_bih = (const float*)d_in[9];
  const float* l0_bhh = (const float*)d_in[10];
  const float* fe1_W1 = (const float*)d_in[11];
  const float* fe1_b1 = (const float*)d_in[12];
  const float* fe1_W2 = (const float*)d_in[13];
  const float* fe1_b2 = (const float*)d_in[14];
  const float* l1_Wih = (const float*)d_in[15];
  const float* l1_Whh = (const float*)d_in[16];
  const float* l1_bih = (const float*)d_in[17];
  const float* l1_bhh = (const float*)d_in[18];
  const float* gm_W   = (const float*)d_in[19];
  const float* gm_b   = (const float*)d_in[20];
  const float* fm_W   = (const float*)d_in[21];
  const float* fm_b   = (const float*)d_in[22];

  const int N = in_sizes[0] / 64;    // 50000
  const int E = in_sizes[1] / 32;    // 800000
  const int* srcI = ei;
  const int* dstI = ei + E;

  char* ws = (char*)d_ws;
  unsigned short* xb0     = (unsigned short*)(ws + 0);           //  6,400,000
  unsigned short* xb1     = (unsigned short*)(ws + 6400000);     //  6,400,000
  float*          aggrH   = (float*)(ws + 12800000);             // 12,800,000
  float*          cbuf    = (float*)(ws + 25600000);             // 12,800,000
  unsigned short* eaS     = (unsigned short*)(ws + 38400000);    // 51,200,000
  int*            srcS    = (int*)(ws + 89601024);               //  3,200,000 (+1KB slack)
  int4*           segInfo = (int4*)(ws + 92801088);              //  1,600,128
  int*            histA   = (int*)(ws + 94401280);               //    200,000
  int*            curA    = (int*)(ws + 94601280);               //    200,000
  unsigned short* W1T     = (unsigned short*)(ws + 94801280);    //     40,960
  unsigned short* WcT     = (unsigned short*)(ws + 94842240);    //    131,072
  float*          bG      = (float*)(ws + 94973312);             //      2,048
  float*          b2h     = (float*)(ws + 94975360);             //      2,048
  unsigned short* WrT     = (unsigned short*)(ws + 94977408);    //     16,384
  int*            nSegPtr = (int*)(ws + 94993792);               //          4 (+60 pad)
  int2*           blockTot  = (int2*)(ws + 94993856);            //      2,048
  int2*           blockBase = (int2*)(ws + 94995904);            //      2,048

  // prep_all covers: weight prep (61952) + merge (33280) + x-convert (N*8)
  //                + aggrH zero (N*16) + histA zero (N/4) + out zero (out_size)
  const int prepT = (2 * 26880 + 8192) + 33280 + N * 8 + N * 16 + N / 4 + out_size;
  prep_all<<<(prepT + 255) / 256, 256, 0, stream>>>(
      x,
      fe0_W1, l0_Wih, l0_bih, l0_bhh,
      fe1_W1, l1_Wih, l1_bih, l1_bhh,
      fe0_W2, l0_Whh, fe0_b2,
      fe1_W2, l1_Whh, fe1_b2,
      gm_W, fm_W,
      W1T, WcT, bG, b2h, WrT, xb0,
      aggrH, histA, (float*)d_out, out_size, N);

  const int nb = (N + 255) / 256;
  hist_kernel<<<(E + 255) / 256, 256, 0, stream>>>(dstI, histA, E);
  scan_part<<<nb, 256, 0, stream>>>(histA, blockTot, N);
  scan_mid<<<1, 256, 0, stream>>>(blockTot, blockBase, nSegPtr, nb);
  scan_final<<<nb, 256, 0, stream>>>(histA, blockBase, curA, segInfo, N);
  scatter_perm<<<(E + 63) / 64, 256, 0, stream>>>(srcI, dstI, ea, curA, srcS, eaS, E);

  const int nodeBlocks = (N + 63) / 64;

  // step 0 (lstm3 re-zeroes aggrH for step 1)
  edge_gemm<<<2048, 256, 0, stream>>>(xb0, eaS, srcS, segInfo, nSegPtr,
                                      W1T, fe0_b1, aggrH);
  lstm3<<<nodeBlocks, 256, 0, stream>>>(xb0, aggrH, nullptr, cbuf, WcT, bG, b2h,
                                        histA, xb1, WrT, gm_b, fm_b, (float*)d_out,
                                        N, 1, 0);

  // step 1: LSTM + fused readout (no xb/cbuf writes, no separate readout kernel)
  edge_gemm<<<2048, 256, 0, stream>>>(xb1, eaS, srcS, segInfo, nSegPtr,
                                      W1T + 10240, fe1_b1, aggrH);
  lstm3<<<nodeBlocks, 256, 0, stream>>>(xb1, aggrH, cbuf, nullptr, WcT + 32768,
                                        bG + 256, b2h + 256, histA, nullptr,
                                        WrT, gm_b, fm_b, (float*)d_out,
                                        N, 0, 1);
}

// Round 11
// 424.298 us; speedup vs baseline: 1.1256x; 1.0548x over previous
//
#include <hip/hip_runtime.h>
#include <hip/hip_bf16.h>

using short8 = __attribute__((ext_vector_type(8))) short;
using f32x4  = __attribute__((ext_vector_type(4))) float;

#define KLP 136   // padded K=128 row stride for LSTM

__device__ __forceinline__ unsigned short f2bf(float f) {
  unsigned u = __float_as_uint(f);
  u += 0x7FFFu + ((u >> 16) & 1u);
  return (unsigned short)(u >> 16);
}
__device__ __forceinline__ unsigned pack2(float a, float b) {
  return (unsigned)f2bf(a) | ((unsigned)f2bf(b) << 16);
}
#if __has_builtin(__builtin_amdgcn_rcpf)
__device__ __forceinline__ float fast_rcp(float x) { return __builtin_amdgcn_rcpf(x); }
#else
__device__ __forceinline__ float fast_rcp(float x) { return 1.f / x; }
#endif
__device__ __forceinline__ float sigm(float x) { return fast_rcp(1.f + __expf(-x)); }
__device__ __forceinline__ float tanh_f(float x) { return fmaf(2.f, sigm(2.f * x), -1.f); }

// ---------------- prep_all: weight prep + x convert + all zero-fills (one dispatch) ----------------
__global__ __launch_bounds__(256) void prep_all(
    const float* __restrict__ x,
    const float* __restrict__ W1_0, const float* __restrict__ Wih0,
    const float* __restrict__ bih0, const float* __restrict__ bhh0,
    const float* __restrict__ W1_1, const float* __restrict__ Wih1,
    const float* __restrict__ bih1, const float* __restrict__ bhh1,
    const float* __restrict__ W2_0, const float* __restrict__ Whh0, const float* __restrict__ b2_0,
    const float* __restrict__ W2_1, const float* __restrict__ Whh1, const float* __restrict__ b2_1,
    const float* __restrict__ gmW, const float* __restrict__ fmW,
    unsigned short* __restrict__ W1T,  // [2][64*160] out-major
    unsigned short* __restrict__ WcT,  // [2][256*128] out-major (merged)
    float* __restrict__ bG,            // [2][256]
    float* __restrict__ b2h,           // [2][256]
    unsigned short* __restrict__ WrT,  // [128][64]
    unsigned short* __restrict__ xb0,  // [N][64] bf16
    float* __restrict__ aggrH,         // [N][64] zeroed here
    int* __restrict__ histA,           // [N]     zeroed here
    float* __restrict__ outZ, int nOut,
    int N)
{
  int t = blockIdx.x * 256 + threadIdx.x;

  // R0: weight transposes (61952 items)
  const int R0 = 2 * 26880 + 8192;
  if (t < R0) {
    const int per = 26880;
    if (t >= 2 * per) {
      int r2 = t - 2 * per;
      int o = r2 >> 6, k = r2 & 63;
      float v = 0.f;
      if (o < 50) v = gmW[k * 50 + o];
      else if (o >= 64 && o < 114) v = fmW[k * 50 + (o - 64)];
      WrT[o * 64 + k] = f2bf(v);
      return;
    }
    int step = t / per, r = t % per;
    const float* W1  = step ? W1_1 : W1_0;
    const float* Wih = step ? Wih1 : Wih0;
    const float* bih = step ? bih1 : bih0;
    const float* bhh = step ? bhh1 : bhh0;
    if (r < 10240) {
      int o = r / 160, k = r % 160;
      W1T[step * 10240 + o * 160 + k] = f2bf(W1[k * 64 + o]);
    } else if (r < 26624) {
      int rr = r - 10240;
      int g = rr >> 6, k = rr & 63;
      WcT[step * 32768 + g * 128 + k] = f2bf(Wih[k * 256 + g]);
    } else {
      int g = r - 26624;
      bG[step * 256 + g] = bih[g] + bhh[g];
    }
    return;
  }
  t -= R0;

  // R1: merged weight  Wc_h' = W2 @ Whh, b2h = b2 @ Whh (33280 items)
  const int R1 = 33280;
  if (t < R1) {
    if (t < 32768) {
      int step = t >> 14, r = t & 16383;
      int g = r >> 6, k = r & 63;
      const float* W2  = step ? W2_1 : W2_0;
      const float* Whh = step ? Whh1 : Whh0;
      float v = 0.f;
      for (int j = 0; j < 64; ++j) v = fmaf(W2[k * 64 + j], Whh[j * 256 + g], v);
      WcT[step * 32768 + g * 128 + 64 + k] = f2bf(v);
    } else {
      int r = t - 32768;
      int step = r >> 8, g = r & 255;
      const float* b2  = step ? b2_1 : b2_0;
      const float* Whh = step ? Whh1 : Whh0;
      float v = 0.f;
      for (int j = 0; j < 64; ++j) v = fmaf(b2[j], Whh[j * 256 + g], v);
      b2h[step * 256 + g] = v;
    }
    return;
  }
  t -= R1;

  // R2: convert_x, 8 elems/thread (N*8 items)
  const int R2 = N * 8;
  if (t < R2) {
    const float4* p = (const float4*)(x + (long long)t * 8);
    float4 a0 = p[0], a1 = p[1];
    *(uint4*)(xb0 + (long long)t * 8) =
        make_uint4(pack2(a0.x, a0.y), pack2(a0.z, a0.w), pack2(a1.x, a1.y), pack2(a1.z, a1.w));
    return;
  }
  t -= R2;

  // R3: zero aggrH as float4 (N*16 items)
  const int R3 = N * 16;
  if (t < R3) { ((float4*)aggrH)[t] = make_float4(0.f, 0.f, 0.f, 0.f); return; }
  t -= R3;

  // R4: zero histA as int4 (N/4 items)
  const int R4 = N / 4;
  if (t < R4) { ((int4*)histA)[t] = make_int4(0, 0, 0, 0); return; }
  t -= R4;

  // R5: zero output
  if (t < nOut) outZ[t] = 0.f;
}

// ---------------- sort: hist -> 3-phase scan (+segment build) -> single-pass permute ----------------
__global__ __launch_bounds__(256) void hist_kernel(
    const int* __restrict__ dstI, int* __restrict__ hist, int E)
{
  int e = blockIdx.x * 256 + threadIdx.x;
  if (e < E) atomicAdd(&hist[dstI[e]], 1);
}

__global__ __launch_bounds__(256) void scan_part(
    const int* __restrict__ hist, int2* __restrict__ blockTot, int N)
{
  __shared__ int sD[256], sS[256];
  int t = threadIdx.x;
  int n = blockIdx.x * 256 + t;
  int d = (n < N) ? hist[n] : 0;
  int sg = (d + 15) >> 4;
  sD[t] = d; sS[t] = sg;
  __syncthreads();
  #pragma unroll
  for (int off = 128; off; off >>= 1) {
    if (t < off) { sD[t] += sD[t + off]; sS[t] += sS[t + off]; }
    __syncthreads();
  }
  if (t == 0) blockTot[blockIdx.x] = make_int2(sD[0], sS[0]);
}

__global__ __launch_bounds__(256) void scan_mid(
    const int2* __restrict__ blockTot, int2* __restrict__ blockBase,
    int* __restrict__ nSegTot, int nb)
{
  __shared__ int sD[256], sS[256];
  int t = threadIdx.x;
  int d = 0, s = 0;
  if (t < nb) { int2 v = blockTot[t]; d = v.x; s = v.y; }
  sD[t] = d; sS[t] = s;
  __syncthreads();
  #pragma unroll
  for (int off = 1; off < 256; off <<= 1) {
    int vd = (t >= off) ? sD[t - off] : 0;
    int vs = (t >= off) ? sS[t - off] : 0;
    __syncthreads();
    sD[t] += vd; sS[t] += vs;
    __syncthreads();
  }
  if (t < nb) blockBase[t] = make_int2(sD[t] - d, sS[t] - s);
  if (t == nb - 1) *nSegTot = sS[t];
}

__global__ __launch_bounds__(256) void scan_final(
    const int* __restrict__ hist, const int2* __restrict__ blockBase,
    int* __restrict__ cursor, int4* __restrict__ segInfo, int N)
{
  __shared__ int sD[256], sS[256];
  int t = threadIdx.x;
  int n = blockIdx.x * 256 + t;
  int d = (n < N) ? hist[n] : 0;
  int sg = (d + 15) >> 4;
  sD[t] = d; sS[t] = sg;
  __syncthreads();
  #pragma unroll
  for (int off = 1; off < 256; off <<= 1) {
    int vd = (t >= off) ? sD[t - off] : 0;
    int vs = (t >= off) ? sS[t - off] : 0;
    __syncthreads();
    sD[t] += vd; sS[t] += vs;
    __syncthreads();
  }
  if (n < N) {
    int2 bb = blockBase[blockIdx.x];
    int degBase = bb.x + sD[t] - d;
    int segBase = bb.y + sS[t] - sg;
    cursor[n] = degBase;
    for (int j = 0; j < sg; ++j)
      segInfo[segBase + j] = make_int4(degBase + j * 16, n, min(d - j * 16, 16), 0);
  }
}

// single-pass permute, 4 lanes per edge: leader does the atomic, __shfl broadcasts p.
// Plain cached stores (round-10 counters: nt-store did NOT cut WRITE_SIZE and
// broke downstream eaS L2/L3 locality -- the 2x write amp is sector-structural).
__global__ __launch_bounds__(256) void scatter_perm(
    const int* __restrict__ srcI, const int* __restrict__ dstI,
    const float* __restrict__ ea, int* __restrict__ cursor,
    int* __restrict__ srcS, unsigned short* __restrict__ eaS, int E)
{
  const int t = threadIdx.x;
  const int l = t & 63;
  const int e = blockIdx.x * 64 + (t >> 2);
  const int c = t & 3;
  if (e >= E) return;
  int p = 0;
  if (c == 0) {
    int d = dstI[e];
    p = atomicAdd(&cursor[d], 1);
    srcS[p] = srcI[e];
  }
  p = __shfl(p, l & ~3);   // broadcast within the 4-lane group
  const float4* pe = (const float4*)(ea + (long long)e * 32 + c * 8);
  float4 a0 = pe[0], a1 = pe[1];
  *(uint4*)(eaS + (long long)p * 32 + c * 8) =
      make_uint4(pack2(a0.x, a0.y), pack2(a0.z, a0.w), pack2(a1.x, a1.y), pack2(a1.z, a1.w));
}

// ---------------- dst_gemm: D[node] = x[node] @ W1[dst-part] + b1  (N x 64 . 64 x 64) ----------------
// The dst contribution is identical for every edge of a node; hoisting it here
// removes 8 of edge_gemm's 20 MFMAs (which computed 16 identical rows each).
__global__ __launch_bounds__(256) void dst_gemm(
    const unsigned short* __restrict__ xb,   // [N][64] bf16
    const unsigned short* __restrict__ W1T,  // [64][160] out-major (kc 0,1 = dst part)
    const float* __restrict__ b1,            // [64]
    float* __restrict__ D,                   // [N][64] f32 out
    int nNodes)
{
  __shared__ unsigned short sX[64 * 72];
  const int t = threadIdx.x;
  const int base = blockIdx.x * 64;
  const int nl = t >> 2, q = t & 3;
  const int node = base + nl;
  {
    uint4* dst = (uint4*)(sX + nl * 72 + q * 16);
    if (node < nNodes) {
      const uint4* px = (const uint4*)(xb + (long long)node * 64);
      dst[0] = px[q * 2];
      dst[1] = px[q * 2 + 1];
    } else {
      dst[0] = make_uint4(0, 0, 0, 0);
      dst[1] = make_uint4(0, 0, 0, 0);
    }
  }
  const int w = t >> 6, l = t & 63, quad = l >> 4, lr = l & 15;
  short8 bF[2][4];
  #pragma unroll
  for (int kc = 0; kc < 2; ++kc)
    #pragma unroll
    for (int n = 0; n < 4; ++n)
      bF[kc][n] = *(const short8*)(W1T + (n * 16 + lr) * 160 + kc * 32 + quad * 8);
  float bb[4];
  #pragma unroll
  for (int n = 0; n < 4; ++n) bb[n] = b1[n * 16 + lr];
  __syncthreads();

  f32x4 acc[4] = {};
  #pragma unroll
  for (int kc = 0; kc < 2; ++kc) {
    short8 aF = *(const short8*)(sX + (w * 16 + lr) * 72 + kc * 32 + quad * 8);
    #pragma unroll
    for (int n = 0; n < 4; ++n)
      acc[n] = __builtin_amdgcn_mfma_f32_16x16x32_bf16(aF, bF[kc][n], acc[n], 0, 0, 0);
  }
  #pragma unroll
  for (int n = 0; n < 4; ++n) {
    #pragma unroll
    for (int rr = 0; rr < 4; ++rr) {
      int nd = base + w * 16 + quad * 4 + rr;
      if (nd < nNodes)
        D[(long long)nd * 64 + n * 16 + lr] = acc[n][rr] + bb[n];
    }
  }
}

// ---------------- edge GEMM: src+ea only (12 MFMA), LDS stash, D-row prefetch ----------------
// wave = one 16-edge segment of one dst node. NOTE: do NOT add registers here --
// round-8's +32-VGPR variant crossed an occupancy cliff (+25us). This version
// REMOVES registers (no pd/a0/a1, no bias regs net).
__global__ __launch_bounds__(256) void edge_gemm(
    const unsigned short* __restrict__ xb,     // [N][64] bf16
    const unsigned short* __restrict__ eaS,    // [E][32] bf16, dst-sorted
    const int* __restrict__ srcS,              // [E] dst-sorted
    const int4* __restrict__ segInfo,          // [nSeg] {start,node,cnt,_}
    const int* __restrict__ nSegPtr,
    const unsigned short* __restrict__ W1T,    // [64][160] bf16 out-major (kc 2..4 used)
    const float* __restrict__ D,               // [N][64] dst-part + b1 (precomputed)
    float* __restrict__ aggrH)                 // [N][64] f32 (pre-zeroed)
{
  __shared__ unsigned short stash[12 * 64 * 8];  // 12 KB: kc=2,3,4 fragments
  const int t = threadIdx.x;
  const int w = t >> 6, l = t & 63;
  const int quad = l >> 4, lr = l & 15;

  #pragma unroll
  for (int p = 0; p < 3; ++p) {
    int idx = p * 256 + t;              // 0..767
    int grp = idx >> 6, ll = idx & 63;  // grp = (kc-2)*4+n
    int kc = 2 + (grp >> 2), n = grp & 3;
    *(uint4*)(stash + idx * 8) =
        *(const uint4*)(W1T + (n * 16 + (ll & 15)) * 160 + kc * 32 + (ll >> 4) * 8);
  }
  __syncthreads();

  const int nSeg = *nSegPtr;
  const int W = gridDim.x * 4;
  int s = blockIdx.x * 4 + w;
  if (s >= nSeg) return;
  int4 si = segInfo[s];
  int src = srcS[si.x + min(lr, si.z - 1)];   // first segment's src, loaded early
  float Dv0, Dv1, Dv2, Dv3;
  {
    const float* dp = D + (long long)si.y * 64 + lr;
    Dv0 = dp[0]; Dv1 = dp[16]; Dv2 = dp[32]; Dv3 = dp[48];
  }

  while (true) {
    const int sn = s + W;
    const bool more = sn < nSeg;
    int4 si_n = si;
    if (more) si_n = segInfo[sn];   // prefetch next descriptor

    const int start = si.x, node = si.y, cnt = si.z;
    const int er = min(lr, cnt - 1);            // clamp pad rows to a valid edge

    const short8* ps = (const short8*)(xb + (long long)src * 64);
    short8 a2 = ps[quad];       // x[src], k 64..95
    short8 a3 = ps[4 + quad];   // x[src], k 96..127
    short8 a4 = *(const short8*)(eaS + (long long)(start + er) * 32 + quad * 8);  // ea, coalesced

    // prefetch next segment's src index + D row while MFMAs run
    int src_n = src;
    float Dn0 = Dv0, Dn1 = Dv1, Dn2 = Dv2, Dn3 = Dv3;
    if (more) {
      src_n = srcS[si_n.x + min(lr, si_n.z - 1)];
      const float* dp = D + (long long)si_n.y * 64 + lr;
      Dn0 = dp[0]; Dn1 = dp[16]; Dn2 = dp[32]; Dn3 = dp[48];
    }

    f32x4 acc[4] = {};
    #pragma unroll
    for (int kc = 0; kc < 3; ++kc) {
      short8 aX = (kc == 0) ? a2 : (kc == 1) ? a3 : a4;
      #pragma unroll
      for (int n = 0; n < 4; ++n) {
        short8 bFr = *(const short8*)(stash + (((kc << 2) | n) * 64 + l) * 8);
        acc[n] = __builtin_amdgcn_mfma_f32_16x16x32_bf16(aX, bFr, acc[n], 0, 0, 0);
      }
    }

    // relu + mask pad rows + reduce; one 64-lane atomic instruction per segment
    float myv = 0.f;
    #pragma unroll
    for (int n = 0; n < 4; ++n) {
      float bias = (n == 0) ? Dv0 : (n == 1) ? Dv1 : (n == 2) ? Dv2 : Dv3;
      float sum = 0.f;
      #pragma unroll
      for (int rr = 0; rr < 4; ++rr) {
        float v = fmaxf(acc[n][rr] + bias, 0.f);
        sum += (quad * 4 + rr < cnt) ? v : 0.f;
      }
      sum += __shfl_xor(sum, 16);
      sum += __shfl_xor(sum, 32);
      if (quad == n) myv = sum;     // lane l owns output column l = quad*16+lr
    }
    unsafeAtomicAdd(&aggrH[(long long)node * 64 + l], myv);

    if (!more) break;
    s = sn; si = si_n; src = src_n;
    Dv0 = Dn0; Dv1 = Dn1; Dv2 = Dn2; Dv3 = Dn3;
  }
}

// ---------------- LSTM cell (+ optional fused readout on the final step) ----------------
__global__ __launch_bounds__(256) void lstm3(
    const unsigned short* __restrict__ xbin,  // [N][64] bf16
    float* __restrict__ aggrH,                // [N][64] f32 (Sum relu h1); re-zeroed if zeroAggr
    const float* __restrict__ cin,            // may be null (c=0)
    float* __restrict__ cout,
    const unsigned short* __restrict__ WcT,   // [256][128] bf16 out-major (merged)
    const float* __restrict__ bG,             // [256]
    const float* __restrict__ b2h,            // [256]
    const int* __restrict__ degA,             // [N]
    unsigned short* __restrict__ xbout,       // [N][64] bf16 (unused if doReadout)
    const unsigned short* __restrict__ WrT,   // [128][64] readout weights (doReadout only)
    const float* __restrict__ gb, const float* __restrict__ fb,
    float* __restrict__ outG,                 // [50] (doReadout only)
    int nNodes, int zeroAggr, int doReadout)
{
  __shared__ unsigned short sIn[64 * KLP];    // 8704 ush; reused as readout X [64][72]
  __shared__ unsigned short sW[128 * 72];     // 9216 ush >= 64*KLP; reused as readout W stash
  __shared__ float sBG[256], sB2h[256];       // reused as readout biases / partial out
  const int t = threadIdx.x;
  sBG[t] = bG[t];
  sB2h[t] = b2h[t];

  const int base_n = blockIdx.x * 64;
  const int nl = t >> 2, q = t & 3;
  const int node = base_n + nl;
  unsigned short* rowp = sIn + nl * KLP;
  if (node < nNodes) {
    const uint4* px = (const uint4*)(xbin + (long long)node * 64);
    *(uint4*)(rowp + q * 16)     = px[q * 2];
    *(uint4*)(rowp + q * 16 + 8) = px[q * 2 + 1];
    float4* pg = (float4*)(aggrH + (long long)node * 64) + q * 4;
    float4 g0 = pg[0], g1 = pg[1], g2 = pg[2], g3 = pg[3];
    *(uint4*)(rowp + 64 + q * 16) =
        make_uint4(pack2(g0.x, g0.y), pack2(g0.z, g0.w), pack2(g1.x, g1.y), pack2(g1.z, g1.w));
    *(uint4*)(rowp + 64 + q * 16 + 8) =
        make_uint4(pack2(g2.x, g2.y), pack2(g2.z, g2.w), pack2(g3.x, g3.y), pack2(g3.z, g3.w));
    if (zeroAggr) {  // re-zero for the next edge_gemm pass (saves a memset dispatch)
      float4 z = make_float4(0.f, 0.f, 0.f, 0.f);
      pg[0] = z; pg[1] = z; pg[2] = z; pg[3] = z;
    }
  } else {
    *(uint4*)(rowp + q * 16)          = make_uint4(0, 0, 0, 0);
    *(uint4*)(rowp + q * 16 + 8)      = make_uint4(0, 0, 0, 0);
    *(uint4*)(rowp + 64 + q * 16)     = make_uint4(0, 0, 0, 0);
    *(uint4*)(rowp + 64 + q * 16 + 8) = make_uint4(0, 0, 0, 0);
  }

  const int w = t >> 6, l = t & 63, quad = l >> 4, lr = l & 15;
  const int row0 = w * 16;
  f32x4 acc[16] = {};
  for (int grp = 0; grp < 4; ++grp) {
    const uint4* gw = (const uint4*)WcT + (long long)(grp * 64) * 16;  // 16 uint4/row
    uint4* lw = (uint4*)sW;                                            // 17/row padded
    {
      int o0 = t >> 4, s4 = t & 15;
      #pragma unroll
      for (int pp = 0; pp < 4; ++pp) {
        int o = pp * 16 + o0;
        lw[o * 17 + s4] = gw[o * 16 + s4];
      }
    }
    __syncthreads();
    #pragma unroll
    for (int kc = 0; kc < 4; ++kc) {
      short8 aF = *(const short8*)(sIn + (row0 + lr) * KLP + kc * 32 + quad * 8);
      #pragma unroll
      for (int nt = 0; nt < 4; ++nt) {
        short8 bF = *(const short8*)(sW + (nt * 16 + lr) * KLP + kc * 32 + quad * 8);
        acc[grp * 4 + nt] = __builtin_amdgcn_mfma_f32_16x16x32_bf16(aF, bF, acc[grp * 4 + nt], 0, 0, 0);
      }
    }
    __syncthreads();
  }

  #pragma unroll
  for (int nt = 0; nt < 4; ++nt) {
    #pragma unroll
    for (int rr = 0; rr < 4; ++rr) {
      int node2 = base_n + row0 + quad * 4 + rr;
      int rl = row0 + quad * 4 + rr;          // block-local row 0..63
      int col = nt * 16 + lr;
      if (node2 < nNodes) {
        long long off = (long long)node2 * 64 + col;
        float dg = (float)degA[node2];
        float iv = acc[nt][rr]      + sBG[col]       + dg * sB2h[col];
        float fv = acc[4 + nt][rr]  + sBG[64 + col]  + dg * sB2h[64 + col];
        float gv = acc[8 + nt][rr]  + sBG[128 + col] + dg * sB2h[128 + col];
        float ov = acc[12 + nt][rr] + sBG[192 + col] + dg * sB2h[192 + col];
        float cOld = cin ? cin[off] : 0.f;
        float cN = sigm(fv) * cOld + sigm(iv) * tanh_f(gv);
        float hN = sigm(ov) * tanh_f(cN);
        if (doReadout) {
          sIn[rl * 72 + col] = f2bf(hN);     // stage h for in-kernel readout
        } else {
          cout[off] = cN;
          xbout[off] = f2bf(hN);
        }
      } else if (doReadout) {
        sIn[rl * 72 + col] = 0;
      }
    }
  }

  if (!doReadout) return;

  // ---------------- fused readout phase (reuses all LDS) ----------------
  __syncthreads();
  {
    const uint4* gw = (const uint4*)WrT;  // 1024 uint4
    uint4* lw = (uint4*)sW;               // 9/row padded -> 72-ush row stride
    #pragma unroll
    for (int pp = 0; pp < 4; ++pp) {
      int idx = t + pp * 256;
      int o = idx >> 3, s = idx & 7;
      lw[o * 9 + s] = gw[idx];
    }
  }
  if (t < 64) {
    sBG[t]      = (t < 50) ? gb[t] : 0.f;   // sGb
    sBG[64 + t] = (t < 50) ? fb[t] : 0.f;   // sFb
  }
  __syncthreads();

  f32x4 racc[8] = {};
  #pragma unroll
  for (int kc = 0; kc < 2; ++kc) {
    short8 aF = *(const short8*)(sIn + (w * 16 + lr) * 72 + kc * 32 + quad * 8);
    #pragma unroll
    for (int n = 0; n < 8; ++n) {
      short8 bF = *(const short8*)(sW + (n * 16 + lr) * 72 + kc * 32 + quad * 8);
      racc[n] = __builtin_amdgcn_mfma_f32_16x16x32_bf16(aF, bF, racc[n], 0, 0, 0);
    }
  }
  float* sOutF = sB2h;   // [4][64] partials
  #pragma unroll
  for (int n = 0; n < 4; ++n) {
    float val = 0.f;
    #pragma unroll
    for (int rr = 0; rr < 4; ++rr) {
      int nd = base_n + w * 16 + quad * 4 + rr;
      if (nd < nNodes) {
        int jj = n * 16 + lr;
        float gv = sigm(racc[n][rr] + sBG[jj]);
        float fv = racc[n + 4][rr] + sBG[64 + jj];
        val += gv * fv;
      }
    }
    val += __shfl_xor(val, 16);
    val += __shfl_xor(val, 32);
    if (quad == 0) sOutF[w * 64 + n * 16 + lr] = val;
  }
  __syncthreads();
  if (t < 50) {
    float sm = sOutF[t] + sOutF[64 + t] + sOutF[128 + t] + sOutF[192 + t];
    unsafeAtomicAdd(&outG[t], sm);
  }
}

extern "C" void kernel_launch(void* const* d_in, const int* in_sizes, int n_in,
                              void* d_out, int out_size, void* d_ws, size_t ws_size,
                              hipStream_t stream)
{
  const float* x      = (const float*)d_in[0];
  const float* ea     = (const float*)d_in[1];
  const int*   ei     = (const int*)d_in[2];
  const float* fe0_W1 = (const float*)d_in[3];
  const float* fe0_b1 = (const float*)d_in[4];
  const float* fe0_W2 = (const float*)d_in[5];
  const float* fe0_b2 = (const float*)d_in[6];
  const float* l0_Wih = (const float*)d_in[7];
  const float* l0_Whh = (const float*)d_in[8];
  const float* l0_bih = (const float*)d_in[9];
  const float* l0_bhh = (const float*)d_in[10];
  const float* fe1_W1 = (const float*)d_in[11];
  const float* fe1_b1 = (const float*)d_in[12];
  const float* fe1_W2 = (const float*)d_in[13];
  const float* fe1_b2 = (const float*)d_in[14];
  const float* l1_Wih = (const float*)d_in[15];
  const float* l1_Whh = (const float*)d_in[16];
  const float* l1_bih = (const float*)d_in[17];
  const float* l1_bhh = (const float*)d_in[18];
  const float* gm_W   = (const float*)d_in[19];
  const float* gm_b   = (const float*)d_in[20];
  const float* fm_W   = (const float*)d_in[21];
  const float* fm_b   = (const float*)d_in[22];

  const int N = in_sizes[0] / 64;    // 50000
  const int E = in_sizes[1] / 32;    // 800000
  const int* srcI = ei;
  const int* dstI = ei + E;

  char* ws = (char*)d_ws;
  unsigned short* xb0     = (unsigned short*)(ws + 0);           //  6,400,000
  unsigned short* xb1     = (unsigned short*)(ws + 6400000);     //  6,400,000
  float*          aggrH   = (float*)(ws + 12800000);             // 12,800,000
  float*          cbuf    = (float*)(ws + 25600000);             // 12,800,000
  unsigned short* eaS     = (unsigned short*)(ws + 38400000);    // 51,200,000
  int*            srcS    = (int*)(ws + 89601024);               //  3,200,000 (+1KB slack)
  int4*           segInfo = (int4*)(ws + 92801088);              //  1,600,128
  int*            histA   = (int*)(ws + 94401280);               //    200,000
  int*            curA    = (int*)(ws + 94601280);               //    200,000
  unsigned short* W1T     = (unsigned short*)(ws + 94801280);    //     40,960
  unsigned short* WcT     = (unsigned short*)(ws + 94842240);    //    131,072
  float*          bG      = (float*)(ws + 94973312);             //      2,048
  float*          b2h     = (float*)(ws + 94975360);             //      2,048
  unsigned short* WrT     = (unsigned short*)(ws + 94977408);    //     16,384
  int*            nSegPtr = (int*)(ws + 94993792);               //          4 (+60 pad)
  int2*           blockTot  = (int2*)(ws + 94993856);            //      2,048
  int2*           blockBase = (int2*)(ws + 94995904);            //      2,048
  float*          Dbuf    = (float*)(ws + 96000000);             // 12,800,000 (dst-part + b1)

  // prep_all covers: weight prep (61952) + merge (33280) + x-convert (N*8)
  //                + aggrH zero (N*16) + histA zero (N/4) + out zero (out_size)
  const int prepT = (2 * 26880 + 8192) + 33280 + N * 8 + N * 16 + N / 4 + out_size;
  prep_all<<<(prepT + 255) / 256, 256, 0, stream>>>(
      x,
      fe0_W1, l0_Wih, l0_bih, l0_bhh,
      fe1_W1, l1_Wih, l1_bih, l1_bhh,
      fe0_W2, l0_Whh, fe0_b2,
      fe1_W2, l1_Whh, fe1_b2,
      gm_W, fm_W,
      W1T, WcT, bG, b2h, WrT, xb0,
      aggrH, histA, (float*)d_out, out_size, N);

  const int nb = (N + 255) / 256;
  hist_kernel<<<(E + 255) / 256, 256, 0, stream>>>(dstI, histA, E);
  scan_part<<<nb, 256, 0, stream>>>(histA, blockTot, N);
  scan_mid<<<1, 256, 0, stream>>>(blockTot, blockBase, nSegPtr, nb);
  scan_final<<<nb, 256, 0, stream>>>(histA, blockBase, curA, segInfo, N);
  scatter_perm<<<(E + 63) / 64, 256, 0, stream>>>(srcI, dstI, ea, curA, srcS, eaS, E);

  const int nodeBlocks = (N + 63) / 64;

  // step 0 (lstm3 re-zeroes aggrH for step 1)
  dst_gemm<<<nodeBlocks, 256, 0, stream>>>(xb0, W1T, fe0_b1, Dbuf, N);
  edge_gemm<<<2048, 256, 0, stream>>>(xb0, eaS, srcS, segInfo, nSegPtr,
                                      W1T, Dbuf, aggrH);
  lstm3<<<nodeBlocks, 256, 0, stream>>>(xb0, aggrH, nullptr, cbuf, WcT, bG, b2h,
                                        histA, xb1, WrT, gm_b, fm_b, (float*)d_out,
                                        N, 1, 0);

  // step 1: LSTM + fused readout (no xb/cbuf writes, no separate readout kernel)
  dst_gemm<<<nodeBlocks, 256, 0, stream>>>(xb1, W1T + 10240, fe1_b1, Dbuf, N);
  edge_gemm<<<2048, 256, 0, stream>>>(xb1, eaS, srcS, segInfo, nSegPtr,
                                      W1T + 10240, Dbuf, aggrH);
  lstm3<<<nodeBlocks, 256, 0, stream>>>(xb1, aggrH, cbuf, nullptr, WcT + 32768,
                                        bG + 256, b2h + 256, histA, nullptr,
                                        WrT, gm_b, fm_b, (float*)d_out,
                                        N, 0, 1);
}

// Round 12
// 423.877 us; speedup vs baseline: 1.1268x; 1.0010x over previous
//
#include <hip/hip_runtime.h>
#include <hip/hip_bf16.h>

using short8 = __attribute__((ext_vector_type(8))) short;
using f32x4  = __attribute__((ext_vector_type(4))) float;

#define KLP 136   // padded K=128 row stride for LSTM

__device__ __forceinline__ unsigned short f2bf(float f) {
  unsigned u = __float_as_uint(f);
  u += 0x7FFFu + ((u >> 16) & 1u);
  return (unsigned short)(u >> 16);
}
__device__ __forceinline__ unsigned pack2(float a, float b) {
  return (unsigned)f2bf(a) | ((unsigned)f2bf(b) << 16);
}
#if __has_builtin(__builtin_amdgcn_rcpf)
__device__ __forceinline__ float fast_rcp(float x) { return __builtin_amdgcn_rcpf(x); }
#else
__device__ __forceinline__ float fast_rcp(float x) { return 1.f / x; }
#endif
__device__ __forceinline__ float sigm(float x) { return fast_rcp(1.f + __expf(-x)); }
__device__ __forceinline__ float tanh_f(float x) { return fmaf(2.f, sigm(2.f * x), -1.f); }

// ---------------- prep_all: weight prep + x convert + all zero-fills (one dispatch) ----------------
__global__ __launch_bounds__(256) void prep_all(
    const float* __restrict__ x,
    const float* __restrict__ W1_0, const float* __restrict__ Wih0,
    const float* __restrict__ bih0, const float* __restrict__ bhh0,
    const float* __restrict__ W1_1, const float* __restrict__ Wih1,
    const float* __restrict__ bih1, const float* __restrict__ bhh1,
    const float* __restrict__ W2_0, const float* __restrict__ Whh0, const float* __restrict__ b2_0,
    const float* __restrict__ W2_1, const float* __restrict__ Whh1, const float* __restrict__ b2_1,
    const float* __restrict__ gmW, const float* __restrict__ fmW,
    unsigned short* __restrict__ W1T,  // [2][64*160] out-major
    unsigned short* __restrict__ WcT,  // [2][256*128] out-major (merged)
    float* __restrict__ bG,            // [2][256]
    float* __restrict__ b2h,           // [2][256]
    unsigned short* __restrict__ WrT,  // [128][64]
    unsigned short* __restrict__ xb0,  // [N][64] bf16
    float* __restrict__ aggrH,         // [N][64] zeroed here
    int* __restrict__ histA,           // [N]     zeroed here
    float* __restrict__ outZ, int nOut,
    int N)
{
  int t = blockIdx.x * 256 + threadIdx.x;

  // R0: weight transposes (61952 items)
  const int R0 = 2 * 26880 + 8192;
  if (t < R0) {
    const int per = 26880;
    if (t >= 2 * per) {
      int r2 = t - 2 * per;
      int o = r2 >> 6, k = r2 & 63;
      float v = 0.f;
      if (o < 50) v = gmW[k * 50 + o];
      else if (o >= 64 && o < 114) v = fmW[k * 50 + (o - 64)];
      WrT[o * 64 + k] = f2bf(v);
      return;
    }
    int step = t / per, r = t % per;
    const float* W1  = step ? W1_1 : W1_0;
    const float* Wih = step ? Wih1 : Wih0;
    const float* bih = step ? bih1 : bih0;
    const float* bhh = step ? bhh1 : bhh0;
    if (r < 10240) {
      int o = r / 160, k = r % 160;
      W1T[step * 10240 + o * 160 + k] = f2bf(W1[k * 64 + o]);
    } else if (r < 26624) {
      int rr = r - 10240;
      int g = rr >> 6, k = rr & 63;
      WcT[step * 32768 + g * 128 + k] = f2bf(Wih[k * 256 + g]);
    } else {
      int g = r - 26624;
      bG[step * 256 + g] = bih[g] + bhh[g];
    }
    return;
  }
  t -= R0;

  // R1: merged weight  Wc_h' = W2 @ Whh, b2h = b2 @ Whh (33280 items)
  const int R1 = 33280;
  if (t < R1) {
    if (t < 32768) {
      int step = t >> 14, r = t & 16383;
      int g = r >> 6, k = r & 63;
      const float* W2  = step ? W2_1 : W2_0;
      const float* Whh = step ? Whh1 : Whh0;
      float v = 0.f;
      for (int j = 0; j < 64; ++j) v = fmaf(W2[k * 64 + j], Whh[j * 256 + g], v);
      WcT[step * 32768 + g * 128 + 64 + k] = f2bf(v);
    } else {
      int r = t - 32768;
      int step = r >> 8, g = r & 255;
      const float* b2  = step ? b2_1 : b2_0;
      const float* Whh = step ? Whh1 : Whh0;
      float v = 0.f;
      for (int j = 0; j < 64; ++j) v = fmaf(b2[j], Whh[j * 256 + g], v);
      b2h[step * 256 + g] = v;
    }
    return;
  }
  t -= R1;

  // R2: convert_x, 8 elems/thread (N*8 items)
  const int R2 = N * 8;
  if (t < R2) {
    const float4* p = (const float4*)(x + (long long)t * 8);
    float4 a0 = p[0], a1 = p[1];
    *(uint4*)(xb0 + (long long)t * 8) =
        make_uint4(pack2(a0.x, a0.y), pack2(a0.z, a0.w), pack2(a1.x, a1.y), pack2(a1.z, a1.w));
    return;
  }
  t -= R2;

  // R3: zero aggrH as float4 (N*16 items)
  const int R3 = N * 16;
  if (t < R3) { ((float4*)aggrH)[t] = make_float4(0.f, 0.f, 0.f, 0.f); return; }
  t -= R3;

  // R4: zero histA as int4 (N/4 items)
  const int R4 = N / 4;
  if (t < R4) { ((int4*)histA)[t] = make_int4(0, 0, 0, 0); return; }
  t -= R4;

  // R5: zero output
  if (t < nOut) outZ[t] = 0.f;
}

// ---------------- sort: hist -> 3-phase scan (+segment build) -> single-pass permute ----------------
__global__ __launch_bounds__(256) void hist_kernel(
    const int* __restrict__ dstI, int* __restrict__ hist, int E)
{
  int e = blockIdx.x * 256 + threadIdx.x;
  if (e < E) atomicAdd(&hist[dstI[e]], 1);
}

__global__ __launch_bounds__(256) void scan_part(
    const int* __restrict__ hist, int2* __restrict__ blockTot, int N)
{
  __shared__ int sD[256], sS[256];
  int t = threadIdx.x;
  int n = blockIdx.x * 256 + t;
  int d = (n < N) ? hist[n] : 0;
  int sg = (d + 15) >> 4;
  sD[t] = d; sS[t] = sg;
  __syncthreads();
  #pragma unroll
  for (int off = 128; off; off >>= 1) {
    if (t < off) { sD[t] += sD[t + off]; sS[t] += sS[t + off]; }
    __syncthreads();
  }
  if (t == 0) blockTot[blockIdx.x] = make_int2(sD[0], sS[0]);
}

__global__ __launch_bounds__(256) void scan_mid(
    const int2* __restrict__ blockTot, int2* __restrict__ blockBase,
    int* __restrict__ nSegTot, int nb)
{
  __shared__ int sD[256], sS[256];
  int t = threadIdx.x;
  int d = 0, s = 0;
  if (t < nb) { int2 v = blockTot[t]; d = v.x; s = v.y; }
  sD[t] = d; sS[t] = s;
  __syncthreads();
  #pragma unroll
  for (int off = 1; off < 256; off <<= 1) {
    int vd = (t >= off) ? sD[t - off] : 0;
    int vs = (t >= off) ? sS[t - off] : 0;
    __syncthreads();
    sD[t] += vd; sS[t] += vs;
    __syncthreads();
  }
  if (t < nb) blockBase[t] = make_int2(sD[t] - d, sS[t] - s);
  if (t == nb - 1) *nSegTot = sS[t];
}

__global__ __launch_bounds__(256) void scan_final(
    const int* __restrict__ hist, const int2* __restrict__ blockBase,
    int* __restrict__ cursor, int4* __restrict__ segInfo, int N)
{
  __shared__ int sD[256], sS[256];
  int t = threadIdx.x;
  int n = blockIdx.x * 256 + t;
  int d = (n < N) ? hist[n] : 0;
  int sg = (d + 15) >> 4;
  sD[t] = d; sS[t] = sg;
  __syncthreads();
  #pragma unroll
  for (int off = 1; off < 256; off <<= 1) {
    int vd = (t >= off) ? sD[t - off] : 0;
    int vs = (t >= off) ? sS[t - off] : 0;
    __syncthreads();
    sD[t] += vd; sS[t] += vs;
    __syncthreads();
  }
  if (n < N) {
    int2 bb = blockBase[blockIdx.x];
    int degBase = bb.x + sD[t] - d;
    int segBase = bb.y + sS[t] - sg;
    cursor[n] = degBase;
    for (int j = 0; j < sg; ++j)
      segInfo[segBase + j] = make_int4(degBase + j * 16, n, min(d - j * 16, 16), 0);
  }
}

// single-pass permute, 4 lanes per edge: leader does the atomic, __shfl broadcasts p.
// ~155MB at ~2.2-2.4 TB/s random-mixed = this phase's measured floor (r0/1/5/6/8/10).
__global__ __launch_bounds__(256) void scatter_perm(
    const int* __restrict__ srcI, const int* __restrict__ dstI,
    const float* __restrict__ ea, int* __restrict__ cursor,
    int* __restrict__ srcS, unsigned short* __restrict__ eaS, int E)
{
  const int t = threadIdx.x;
  const int l = t & 63;
  const int e = blockIdx.x * 64 + (t >> 2);
  const int c = t & 3;
  if (e >= E) return;
  int p = 0;
  if (c == 0) {
    int d = dstI[e];
    p = atomicAdd(&cursor[d], 1);
    srcS[p] = srcI[e];
  }
  p = __shfl(p, l & ~3);   // broadcast within the 4-lane group
  const float4* pe = (const float4*)(ea + (long long)e * 32 + c * 8);
  float4 a0 = pe[0], a1 = pe[1];
  *(uint4*)(eaS + (long long)p * 32 + c * 8) =
      make_uint4(pack2(a0.x, a0.y), pack2(a0.z, a0.w), pack2(a1.x, a1.y), pack2(a1.z, a1.w));
}

// ---------------- dst_gemm: D[node] = x[node] @ W1[dst-part] + b1  (N x 64 . 64 x 64) ----------------
__global__ __launch_bounds__(256) void dst_gemm(
    const unsigned short* __restrict__ xb,   // [N][64] bf16
    const unsigned short* __restrict__ W1T,  // [64][160] out-major (kc 0,1 = dst part)
    const float* __restrict__ b1,            // [64]
    float* __restrict__ D,                   // [N][64] f32 out
    int nNodes)
{
  __shared__ unsigned short sX[64 * 72];
  const int t = threadIdx.x;
  const int base = blockIdx.x * 64;
  const int nl = t >> 2, q = t & 3;
  const int node = base + nl;
  {
    uint4* dst = (uint4*)(sX + nl * 72 + q * 16);
    if (node < nNodes) {
      const uint4* px = (const uint4*)(xb + (long long)node * 64);
      dst[0] = px[q * 2];
      dst[1] = px[q * 2 + 1];
    } else {
      dst[0] = make_uint4(0, 0, 0, 0);
      dst[1] = make_uint4(0, 0, 0, 0);
    }
  }
  const int w = t >> 6, l = t & 63, quad = l >> 4, lr = l & 15;
  short8 bF[2][4];
  #pragma unroll
  for (int kc = 0; kc < 2; ++kc)
    #pragma unroll
    for (int n = 0; n < 4; ++n)
      bF[kc][n] = *(const short8*)(W1T + (n * 16 + lr) * 160 + kc * 32 + quad * 8);
  float bb[4];
  #pragma unroll
  for (int n = 0; n < 4; ++n) bb[n] = b1[n * 16 + lr];
  __syncthreads();

  f32x4 acc[4] = {};
  #pragma unroll
  for (int kc = 0; kc < 2; ++kc) {
    short8 aF = *(const short8*)(sX + (w * 16 + lr) * 72 + kc * 32 + quad * 8);
    #pragma unroll
    for (int n = 0; n < 4; ++n)
      acc[n] = __builtin_amdgcn_mfma_f32_16x16x32_bf16(aF, bF[kc][n], acc[n], 0, 0, 0);
  }
  #pragma unroll
  for (int n = 0; n < 4; ++n) {
    #pragma unroll
    for (int rr = 0; rr < 4; ++rr) {
      int nd = base + w * 16 + quad * 4 + rr;
      if (nd < nNodes)
        D[(long long)nd * 64 + n * 16 + lr] = acc[n][rr] + bb[n];
    }
  }
}

// ---------------- edge GEMM: src+ea (12 MFMA), payload software pipeline ----------------
// wave = one 16-edge segment. Index pipeline 2-deep (segInfo/srcS), payload
// pipeline 1-deep (x[src], eaS, D rows loaded one full iteration before use) --
// round-10 counters showed MfmaUtil 13.8%: the x[src] gather latency was naked
// on the critical path. Target VGPR <= ~100 (5 waves/SIMD; cliff at >102).
__global__ __launch_bounds__(256) void edge_gemm(
    const unsigned short* __restrict__ xb,     // [N][64] bf16
    const unsigned short* __restrict__ eaS,    // [E][32] bf16, dst-sorted
    const int* __restrict__ srcS,              // [E] dst-sorted
    const int4* __restrict__ segInfo,          // [nSeg] {start,node,cnt,_}
    const int* __restrict__ nSegPtr,
    const unsigned short* __restrict__ W1T,    // [64][160] bf16 out-major (kc 2..4 used)
    const float* __restrict__ D,               // [N][64] dst-part + b1 (precomputed)
    float* __restrict__ aggrH)                 // [N][64] f32 (pre-zeroed)
{
  __shared__ unsigned short stash[12 * 64 * 8];  // 12 KB: kc=2,3,4 fragments
  const int t = threadIdx.x;
  const int w = t >> 6, l = t & 63;
  const int quad = l >> 4, lr = l & 15;

  #pragma unroll
  for (int p = 0; p < 3; ++p) {
    int idx = p * 256 + t;              // 0..767
    int grp = idx >> 6, ll = idx & 63;  // grp = (kc-2)*4+n
    int kc = 2 + (grp >> 2), n = grp & 3;
    *(uint4*)(stash + idx * 8) =
        *(const uint4*)(W1T + (n * 16 + (ll & 15)) * 160 + kc * 32 + (ll >> 4) * 8);
  }
  __syncthreads();

  const int nSeg = *nSegPtr;
  const int W = gridDim.x * 4;
  int s = blockIdx.x * 4 + w;
  if (s >= nSeg) return;

  // prologue: current segment fully resolved (indices + payloads)
  int4 si = segInfo[s];
  short8 A2, A3, A4;
  float Dv0, Dv1, Dv2, Dv3;
  {
    int src0 = srcS[si.x + min(lr, si.z - 1)];
    const short8* ps = (const short8*)(xb + (long long)src0 * 64);
    A2 = ps[quad];
    A3 = ps[4 + quad];
    A4 = *(const short8*)(eaS + (long long)(si.x + min(lr, si.z - 1)) * 32 + quad * 8);
    const float* dp = D + (long long)si.y * 64 + lr;
    Dv0 = dp[0]; Dv1 = dp[16]; Dv2 = dp[32]; Dv3 = dp[48];
  }
  // 1-ahead indices
  int sn = s + W;
  bool more = sn < nSeg;
  int4 si_n = si;
  int src_n = 0;
  if (more) {
    si_n = segInfo[sn];
    src_n = srcS[si_n.x + min(lr, si_n.z - 1)];
  }

  while (true) {
    // issue NEXT-segment payload loads (consumed next iteration)
    short8 B2 = A2, B3 = A3, B4 = A4;
    float En0 = Dv0, En1 = Dv1, En2 = Dv2, En3 = Dv3;
    if (more) {
      const short8* ps = (const short8*)(xb + (long long)src_n * 64);
      B2 = ps[quad];
      B3 = ps[4 + quad];
      B4 = *(const short8*)(eaS + (long long)(si_n.x + min(lr, si_n.z - 1)) * 32 + quad * 8);
      const float* dp = D + (long long)si_n.y * 64 + lr;
      En0 = dp[0]; En1 = dp[16]; En2 = dp[32]; En3 = dp[48];
    }
    // 2-ahead indices (predictable addresses, no payload dependency)
    int snn = sn + W;
    bool more2 = more && (snn < nSeg);
    int4 si_nn = si_n;
    int src_nn = src_n;
    if (more2) {
      si_nn = segInfo[snn];
      src_nn = srcS[si_nn.x + min(lr, si_nn.z - 1)];
    }

    // compute on CURRENT (fully resolved) payloads
    const int node = si.y, cnt = si.z;
    f32x4 acc[4] = {};
    #pragma unroll
    for (int kc = 0; kc < 3; ++kc) {
      short8 aX = (kc == 0) ? A2 : (kc == 1) ? A3 : A4;
      #pragma unroll
      for (int n = 0; n < 4; ++n) {
        short8 bFr = *(const short8*)(stash + (((kc << 2) | n) * 64 + l) * 8);
        acc[n] = __builtin_amdgcn_mfma_f32_16x16x32_bf16(aX, bFr, acc[n], 0, 0, 0);
      }
    }

    // relu + mask pad rows + reduce; one 64-lane atomic instruction per segment
    float myv = 0.f;
    #pragma unroll
    for (int n = 0; n < 4; ++n) {
      float bias = (n == 0) ? Dv0 : (n == 1) ? Dv1 : (n == 2) ? Dv2 : Dv3;
      float sum = 0.f;
      #pragma unroll
      for (int rr = 0; rr < 4; ++rr) {
        float v = fmaxf(acc[n][rr] + bias, 0.f);
        sum += (quad * 4 + rr < cnt) ? v : 0.f;
      }
      sum += __shfl_xor(sum, 16);
      sum += __shfl_xor(sum, 32);
      if (quad == n) myv = sum;     // lane l owns output column l = quad*16+lr
    }
    unsafeAtomicAdd(&aggrH[(long long)node * 64 + l], myv);

    if (!more) break;
    // rotate pipeline
    si = si_n; A2 = B2; A3 = B3; A4 = B4;
    Dv0 = En0; Dv1 = En1; Dv2 = En2; Dv3 = En3;
    sn = snn; si_n = si_nn; src_n = src_nn; more = more2;
  }
}

// ---------------- LSTM cell (+ optional fused readout on the final step) ----------------
__global__ __launch_bounds__(256) void lstm3(
    const unsigned short* __restrict__ xbin,  // [N][64] bf16
    float* __restrict__ aggrH,                // [N][64] f32 (Sum relu h1); re-zeroed if zeroAggr
    const float* __restrict__ cin,            // may be null (c=0)
    float* __restrict__ cout,
    const unsigned short* __restrict__ WcT,   // [256][128] bf16 out-major (merged)
    const float* __restrict__ bG,             // [256]
    const float* __restrict__ b2h,            // [256]
    const int* __restrict__ degA,             // [N]
    unsigned short* __restrict__ xbout,       // [N][64] bf16 (unused if doReadout)
    const unsigned short* __restrict__ WrT,   // [128][64] readout weights (doReadout only)
    const float* __restrict__ gb, const float* __restrict__ fb,
    float* __restrict__ outG,                 // [50] (doReadout only)
    int nNodes, int zeroAggr, int doReadout)
{
  __shared__ unsigned short sIn[64 * KLP];    // 8704 ush; reused as readout X [64][72]
  __shared__ unsigned short sW[128 * 72];     // 9216 ush >= 64*KLP; reused as readout W stash
  __shared__ float sBG[256], sB2h[256];       // reused as readout biases / partial out
  const int t = threadIdx.x;
  sBG[t] = bG[t];
  sB2h[t] = b2h[t];

  const int base_n = blockIdx.x * 64;
  const int nl = t >> 2, q = t & 3;
  const int node = base_n + nl;
  unsigned short* rowp = sIn + nl * KLP;
  if (node < nNodes) {
    const uint4* px = (const uint4*)(xbin + (long long)node * 64);
    *(uint4*)(rowp + q * 16)     = px[q * 2];
    *(uint4*)(rowp + q * 16 + 8) = px[q * 2 + 1];
    float4* pg = (float4*)(aggrH + (long long)node * 64) + q * 4;
    float4 g0 = pg[0], g1 = pg[1], g2 = pg[2], g3 = pg[3];
    *(uint4*)(rowp + 64 + q * 16) =
        make_uint4(pack2(g0.x, g0.y), pack2(g0.z, g0.w), pack2(g1.x, g1.y), pack2(g1.z, g1.w));
    *(uint4*)(rowp + 64 + q * 16 + 8) =
        make_uint4(pack2(g2.x, g2.y), pack2(g2.z, g2.w), pack2(g3.x, g3.y), pack2(g3.z, g3.w));
    if (zeroAggr) {  // re-zero for the next edge_gemm pass (saves a memset dispatch)
      float4 z = make_float4(0.f, 0.f, 0.f, 0.f);
      pg[0] = z; pg[1] = z; pg[2] = z; pg[3] = z;
    }
  } else {
    *(uint4*)(rowp + q * 16)          = make_uint4(0, 0, 0, 0);
    *(uint4*)(rowp + q * 16 + 8)      = make_uint4(0, 0, 0, 0);
    *(uint4*)(rowp + 64 + q * 16)     = make_uint4(0, 0, 0, 0);
    *(uint4*)(rowp + 64 + q * 16 + 8) = make_uint4(0, 0, 0, 0);
  }

  const int w = t >> 6, l = t & 63, quad = l >> 4, lr = l & 15;
  const int row0 = w * 16;
  f32x4 acc[16] = {};
  for (int grp = 0; grp < 4; ++grp) {
    const uint4* gw = (const uint4*)WcT + (long long)(grp * 64) * 16;  // 16 uint4/row
    uint4* lw = (uint4*)sW;                                            // 17/row padded
    {
      int o0 = t >> 4, s4 = t & 15;
      #pragma unroll
      for (int pp = 0; pp < 4; ++pp) {
        int o = pp * 16 + o0;
        lw[o * 17 + s4] = gw[o * 16 + s4];
      }
    }
    __syncthreads();
    #pragma unroll
    for (int kc = 0; kc < 4; ++kc) {
      short8 aF = *(const short8*)(sIn + (row0 + lr) * KLP + kc * 32 + quad * 8);
      #pragma unroll
      for (int nt = 0; nt < 4; ++nt) {
        short8 bF = *(const short8*)(sW + (nt * 16 + lr) * KLP + kc * 32 + quad * 8);
        acc[grp * 4 + nt] = __builtin_amdgcn_mfma_f32_16x16x32_bf16(aF, bF, acc[grp * 4 + nt], 0, 0, 0);
      }
    }
    __syncthreads();
  }

  #pragma unroll
  for (int nt = 0; nt < 4; ++nt) {
    #pragma unroll
    for (int rr = 0; rr < 4; ++rr) {
      int node2 = base_n + row0 + quad * 4 + rr;
      int rl = row0 + quad * 4 + rr;          // block-local row 0..63
      int col = nt * 16 + lr;
      if (node2 < nNodes) {
        long long off = (long long)node2 * 64 + col;
        float dg = (float)degA[node2];
        float iv = acc[nt][rr]      + sBG[col]       + dg * sB2h[col];
        float fv = acc[4 + nt][rr]  + sBG[64 + col]  + dg * sB2h[64 + col];
        float gv = acc[8 + nt][rr]  + sBG[128 + col] + dg * sB2h[128 + col];
        float ov = acc[12 + nt][rr] + sBG[192 + col] + dg * sB2h[192 + col];
        float cOld = cin ? cin[off] : 0.f;
        float cN = sigm(fv) * cOld + sigm(iv) * tanh_f(gv);
        float hN = sigm(ov) * tanh_f(cN);
        if (doReadout) {
          sIn[rl * 72 + col] = f2bf(hN);     // stage h for in-kernel readout
        } else {
          cout[off] = cN;
          xbout[off] = f2bf(hN);
        }
      } else if (doReadout) {
        sIn[rl * 72 + col] = 0;
      }
    }
  }

  if (!doReadout) return;

  // ---------------- fused readout phase (reuses all LDS) ----------------
  __syncthreads();
  {
    const uint4* gw = (const uint4*)WrT;  // 1024 uint4
    uint4* lw = (uint4*)sW;               // 9/row padded -> 72-ush row stride
    #pragma unroll
    for (int pp = 0; pp < 4; ++pp) {
      int idx = t + pp * 256;
      int o = idx >> 3, s = idx & 7;
      lw[o * 9 + s] = gw[idx];
    }
  }
  if (t < 64) {
    sBG[t]      = (t < 50) ? gb[t] : 0.f;   // sGb
    sBG[64 + t] = (t < 50) ? fb[t] : 0.f;   // sFb
  }
  __syncthreads();

  f32x4 racc[8] = {};
  #pragma unroll
  for (int kc = 0; kc < 2; ++kc) {
    short8 aF = *(const short8*)(sIn + (w * 16 + lr) * 72 + kc * 32 + quad * 8);
    #pragma unroll
    for (int n = 0; n < 8; ++n) {
      short8 bF = *(const short8*)(sW + (n * 16 + lr) * 72 + kc * 32 + quad * 8);
      racc[n] = __builtin_amdgcn_mfma_f32_16x16x32_bf16(aF, bF, racc[n], 0, 0, 0);
    }
  }
  float* sOutF = sB2h;   // [4][64] partials
  #pragma unroll
  for (int n = 0; n < 4; ++n) {
    float val = 0.f;
    #pragma unroll
    for (int rr = 0; rr < 4; ++rr) {
      int nd = base_n + w * 16 + quad * 4 + rr;
      if (nd < nNodes) {
        int jj = n * 16 + lr;
        float gv = sigm(racc[n][rr] + sBG[jj]);
        float fv = racc[n + 4][rr] + sBG[64 + jj];
        val += gv * fv;
      }
    }
    val += __shfl_xor(val, 16);
    val += __shfl_xor(val, 32);
    if (quad == 0) sOutF[w * 64 + n * 16 + lr] = val;
  }
  __syncthreads();
  if (t < 50) {
    float sm = sOutF[t] + sOutF[64 + t] + sOutF[128 + t] + sOutF[192 + t];
    unsafeAtomicAdd(&outG[t], sm);
  }
}

extern "C" void kernel_launch(void* const* d_in, const int* in_sizes, int n_in,
                              void* d_out, int out_size, void* d_ws, size_t ws_size,
                              hipStream_t stream)
{
  const float* x      = (const float*)d_in[0];
  const float* ea     = (const float*)d_in[1];
  const int*   ei     = (const int*)d_in[2];
  const float* fe0_W1 = (const float*)d_in[3];
  const float* fe0_b1 = (const float*)d_in[4];
  const float* fe0_W2 = (const float*)d_in[5];
  const float* fe0_b2 = (const float*)d_in[6];
  const float* l0_Wih = (const float*)d_in[7];
  const float* l0_Whh = (const float*)d_in[8];
  const float* l0_bih = (const float*)d_in[9];
  const float* l0_bhh = (const float*)d_in[10];
  const float* fe1_W1 = (const float*)d_in[11];
  const float* fe1_b1 = (const float*)d_in[12];
  const float* fe1_W2 = (const float*)d_in[13];
  const float* fe1_b2 = (const float*)d_in[14];
  const float* l1_Wih = (const float*)d_in[15];
  const float* l1_Whh = (const float*)d_in[16];
  const float* l1_bih = (const float*)d_in[17];
  const float* l1_bhh = (const float*)d_in[18];
  const float* gm_W   = (const float*)d_in[19];
  const float* gm_b   = (const float*)d_in[20];
  const float* fm_W   = (const float*)d_in[21];
  const float* fm_b   = (const float*)d_in[22];

  const int N = in_sizes[0] / 64;    // 50000
  const int E = in_sizes[1] / 32;    // 800000
  const int* srcI = ei;
  const int* dstI = ei + E;

  char* ws = (char*)d_ws;
  unsigned short* xb0     = (unsigned short*)(ws + 0);           //  6,400,000
  unsigned short* xb1     = (unsigned short*)(ws + 6400000);     //  6,400,000
  float*          aggrH   = (float*)(ws + 12800000);             // 12,800,000
  float*          cbuf    = (float*)(ws + 25600000);             // 12,800,000
  unsigned short* eaS     = (unsigned short*)(ws + 38400000);    // 51,200,000
  int*            srcS    = (int*)(ws + 89601024);               //  3,200,000 (+1KB slack)
  int4*           segInfo = (int4*)(ws + 92801088);              //  1,600,128
  int*            histA   = (int*)(ws + 94401280);               //    200,000
  int*            curA    = (int*)(ws + 94601280);               //    200,000
  unsigned short* W1T     = (unsigned short*)(ws + 94801280);    //     40,960
  unsigned short* WcT     = (unsigned short*)(ws + 94842240);    //    131,072
  float*          bG      = (float*)(ws + 94973312);             //      2,048
  float*          b2h     = (float*)(ws + 94975360);             //      2,048
  unsigned short* WrT     = (unsigned short*)(ws + 94977408);    //     16,384
  int*            nSegPtr = (int*)(ws + 94993792);               //          4 (+60 pad)
  int2*           blockTot  = (int2*)(ws + 94993856);            //      2,048
  int2*           blockBase = (int2*)(ws + 94995904);            //      2,048
  float*          Dbuf    = (float*)(ws + 96000000);             // 12,800,000 (dst-part + b1)

  // prep_all covers: weight prep (61952) + merge (33280) + x-convert (N*8)
  //                + aggrH zero (N*16) + histA zero (N/4) + out zero (out_size)
  const int prepT = (2 * 26880 + 8192) + 33280 + N * 8 + N * 16 + N / 4 + out_size;
  prep_all<<<(prepT + 255) / 256, 256, 0, stream>>>(
      x,
      fe0_W1, l0_Wih, l0_bih, l0_bhh,
      fe1_W1, l1_Wih, l1_bih, l1_bhh,
      fe0_W2, l0_Whh, fe0_b2,
      fe1_W2, l1_Whh, fe1_b2,
      gm_W, fm_W,
      W1T, WcT, bG, b2h, WrT, xb0,
      aggrH, histA, (float*)d_out, out_size, N);

  const int nb = (N + 255) / 256;
  hist_kernel<<<(E + 255) / 256, 256, 0, stream>>>(dstI, histA, E);
  scan_part<<<nb, 256, 0, stream>>>(histA, blockTot, N);
  scan_mid<<<1, 256, 0, stream>>>(blockTot, blockBase, nSegPtr, nb);
  scan_final<<<nb, 256, 0, stream>>>(histA, blockBase, curA, segInfo, N);
  scatter_perm<<<(E + 63) / 64, 256, 0, stream>>>(srcI, dstI, ea, curA, srcS, eaS, E);

  const int nodeBlocks = (N + 63) / 64;

  // step 0 (lstm3 re-zeroes aggrH for step 1)
  dst_gemm<<<nodeBlocks, 256, 0, stream>>>(xb0, W1T, fe0_b1, Dbuf, N);
  edge_gemm<<<2048, 256, 0, stream>>>(xb0, eaS, srcS, segInfo, nSegPtr,
                                      W1T, Dbuf, aggrH);
  lstm3<<<nodeBlocks, 256, 0, stream>>>(xb0, aggrH, nullptr, cbuf, WcT, bG, b2h,
                                        histA, xb1, WrT, gm_b, fm_b, (float*)d_out,
                                        N, 1, 0);

  // step 1: LSTM + fused readout (no xb/cbuf writes, no separate readout kernel)
  dst_gemm<<<nodeBlocks, 256, 0, stream>>>(xb1, W1T + 10240, fe1_b1, Dbuf, N);
  edge_gemm<<<2048, 256, 0, stream>>>(xb1, eaS, srcS, segInfo, nSegPtr,
                                      W1T + 10240, Dbuf, aggrH);
  lstm3<<<nodeBlocks, 256, 0, stream>>>(xb1, aggrH, cbuf, nullptr, WcT + 32768,
                                        bG + 256, b2h + 256, histA, nullptr,
                                        WrT, gm_b, fm_b, (float*)d_out,
                                        N, 0, 1);
}